// Round 1
// baseline (1054.795 us; speedup 1.0000x reference)
//
#include <hip/hip_runtime.h>
#include <math.h>

#define NTOT 110592   // 48^3
#define SD 48
#define SWD 2304      // 48*48

// ---------------------------------------------------------------------------
// transpose weights: dst[k*128+co] = src[co*K + k]
__global__ __launch_bounds__(256) void k_transpose_w(const float* __restrict__ src,
                                                     float* __restrict__ dst, int K) {
    int idx = blockIdx.x * 256 + threadIdx.x;
    if (idx >= K * 128) return;
    int k = idx >> 7;
    int co = idx & 127;
    dst[idx] = src[co * K + k];
}

// ---------------------------------------------------------------------------
// proj conv (im2col matmul, K=108) + LN(g0,b0) -> t, + LN(g2,b2) -> h
__global__ __launch_bounds__(256) void k_proj_ln(
    const float* __restrict__ x, const float* __restrict__ pwT, const float* __restrict__ pb,
    const float* __restrict__ g0, const float* __restrict__ b0,
    const float* __restrict__ g2, const float* __restrict__ b2,
    float* __restrict__ t_out, float* __restrict__ h_out)
{
    __shared__ float SH[64 * 130];      // used as At (stride 112) then Res (stride 130)
    __shared__ float P1[4][64], P2[4][64], Mrow[64], Rrow[64];
    const int tid = threadIdx.x;
    const int n0 = blockIdx.x * 64;

    // im2col staging: At(r,m) = SH[r*112+m], m in [0,108)
    for (int idx = tid; idx < 64 * 108; idx += 256) {
        int r = idx / 108;
        int m = idx - r * 108;
        int ci = m / 27;  int mm = m - ci * 27;
        int ti = mm / 9;  int mj = mm - ti * 9;
        int tj = mj / 3;  int tk = mj - tj * 3;
        int n = n0 + r;
        int oi = n / SWD; int rem = n - oi * SWD;
        int oj = rem / SD; int ok = rem - oj * SD;
        int ii = 2 * oi + ti - 1;
        int ij = 2 * oj + tj - 1;
        int ik = 2 * ok + tk - 1;
        float v = 0.f;
        if (ii >= 0 && ii < 96 && ij >= 0 && ij < 96 && ik >= 0 && ik < 96)
            v = x[((ci * 96 + ii) * 96 + ij) * 96 + ik];
        SH[r * 112 + m] = v;
    }
    __syncthreads();

    const int tc = tid & 31;
    const int tr = tid >> 5;   // 0..7 -> rows tr*8..tr*8+7
    float acc[8][4];
    {
        float4 bb = *(const float4*)&pb[tc * 4];
        #pragma unroll
        for (int ri = 0; ri < 8; ++ri) {
            acc[ri][0] = bb.x; acc[ri][1] = bb.y; acc[ri][2] = bb.z; acc[ri][3] = bb.w;
        }
    }
    for (int k4 = 0; k4 < 27; ++k4) {
        float4 a[8];
        #pragma unroll
        for (int ri = 0; ri < 8; ++ri)
            a[ri] = *(const float4*)&SH[(tr * 8 + ri) * 112 + k4 * 4];
        #pragma unroll
        for (int kk = 0; kk < 4; ++kk) {
            float4 w = *(const float4*)&pwT[(k4 * 4 + kk) * 128 + tc * 4];
            #pragma unroll
            for (int ri = 0; ri < 8; ++ri) {
                float av = ((const float*)&a[ri])[kk];
                acc[ri][0] = fmaf(av, w.x, acc[ri][0]);
                acc[ri][1] = fmaf(av, w.y, acc[ri][1]);
                acc[ri][2] = fmaf(av, w.z, acc[ri][2]);
                acc[ri][3] = fmaf(av, w.w, acc[ri][3]);
            }
        }
    }
    __syncthreads();   // done reading At region

    // store conv result into Res (stride 130)
    #pragma unroll
    for (int ri = 0; ri < 8; ++ri)
        #pragma unroll
        for (int cj = 0; cj < 4; ++cj)
            SH[(tr * 8 + ri) * 130 + tc * 4 + cj] = acc[ri][cj];
    __syncthreads();

    // LN0 stats
    {
        const int r = tid & 63;
        const int cg = tid >> 6;
        float s1 = 0.f, s2 = 0.f;
        #pragma unroll
        for (int m = 0; m < 32; ++m) {
            float v = SH[r * 130 + cg * 32 + m];
            s1 += v; s2 += v * v;
        }
        P1[cg][r] = s1; P2[cg][r] = s2;
    }
    __syncthreads();
    if (tid < 64) {
        float a = P1[0][tid] + P1[1][tid] + P1[2][tid] + P1[3][tid];
        float b = P2[0][tid] + P2[1][tid] + P2[2][tid] + P2[3][tid];
        float mean = a * (1.f / 128.f);
        float var = fmaxf(b * (1.f / 128.f) - mean * mean, 0.f);
        Mrow[tid] = mean;
        Rrow[tid] = rsqrtf(var + 1e-5f);
    }
    __syncthreads();
    // apply LN0 -> t (in place), accumulate LN2 stats
    {
        const int r = tid & 63;
        const int cg = tid >> 6;
        float mean = Mrow[r], rstd = Rrow[r];
        float s1 = 0.f, s2 = 0.f;
        #pragma unroll
        for (int m = 0; m < 32; ++m) {
            int c = cg * 32 + m;
            float z = (SH[r * 130 + c] - mean) * rstd;
            float tv = z * g0[c] + b0[c];
            SH[r * 130 + c] = tv;
            s1 += tv; s2 += tv * tv;
        }
        P1[cg][r] = s1; P2[cg][r] = s2;
    }
    __syncthreads();
    if (tid < 64) {
        float a = P1[0][tid] + P1[1][tid] + P1[2][tid] + P1[3][tid];
        float b = P2[0][tid] + P2[1][tid] + P2[2][tid] + P2[3][tid];
        float mean = a * (1.f / 128.f);
        float var = fmaxf(b * (1.f / 128.f) - mean * mean, 0.f);
        Mrow[tid] = mean;
        Rrow[tid] = rsqrtf(var + 1e-5f);
    }
    __syncthreads();
    // write t and h (coalesced)
    {
        const int c = tid & 127;
        const int rh = tid >> 7;    // 0..1
        float gg = g2[c], bb2 = b2[c];
        for (int rr = rh; rr < 64; rr += 2) {
            float tv = SH[rr * 130 + c];
            t_out[(size_t)(n0 + rr) * 128 + c] = tv;
            float hv = (tv - Mrow[rr]) * Rrow[rr] * gg + bb2;
            h_out[(size_t)(n0 + rr) * 128 + c] = hv;
        }
    }
}

// ---------------------------------------------------------------------------
// axial shift (fused into A gather) + matmul (out = shift(in) @ W^T + b)
// AXIS: 0 -> H (stride 2304), 1 -> W (stride 48), 2 -> D (stride 1)
template <int AXIS>
__global__ __launch_bounds__(256) void k_shift_mm(
    const float* __restrict__ in, const float* __restrict__ wT, const float* __restrict__ bias,
    float* __restrict__ out)
{
    __shared__ float At[64 * 128];
    const int tid = threadIdx.x;
    const int n0 = blockIdx.x * 64;

    for (int idx = tid; idx < 64 * 128; idx += 256) {
        int c = idx & 127;
        int n = n0 + (idx >> 7);
        int g = c / 26;
        int s = g - 2;
        int coord, src;
        if (AXIS == 0)      { coord = n / SWD;        src = n - s * SWD; }
        else if (AXIS == 1) { coord = (n / SD) % SD;  src = n - s * SD;  }
        else                { coord = n % SD;         src = n - s;       }
        int cs = coord - s;
        float v = (cs >= 0 && cs < SD) ? in[(size_t)src * 128 + c] : 0.f;
        At[idx] = v;
    }
    __syncthreads();

    const int tc = tid & 31;
    const int tr = tid >> 5;
    float acc[8][4];
    {
        float4 bb = *(const float4*)&bias[tc * 4];
        #pragma unroll
        for (int ri = 0; ri < 8; ++ri) {
            acc[ri][0] = bb.x; acc[ri][1] = bb.y; acc[ri][2] = bb.z; acc[ri][3] = bb.w;
        }
    }
    for (int k4 = 0; k4 < 32; ++k4) {
        float4 a[8];
        #pragma unroll
        for (int ri = 0; ri < 8; ++ri)
            a[ri] = *(const float4*)&At[(tr * 8 + ri) * 128 + k4 * 4];
        #pragma unroll
        for (int kk = 0; kk < 4; ++kk) {
            float4 w = *(const float4*)&wT[(k4 * 4 + kk) * 128 + tc * 4];
            #pragma unroll
            for (int ri = 0; ri < 8; ++ri) {
                float av = ((const float*)&a[ri])[kk];
                acc[ri][0] = fmaf(av, w.x, acc[ri][0]);
                acc[ri][1] = fmaf(av, w.y, acc[ri][1]);
                acc[ri][2] = fmaf(av, w.z, acc[ri][2]);
                acc[ri][3] = fmaf(av, w.w, acc[ri][3]);
            }
        }
    }
    #pragma unroll
    for (int ri = 0; ri < 8; ++ri) {
        float4 o;
        o.x = acc[ri][0]; o.y = acc[ri][1]; o.z = acc[ri][2]; o.w = acc[ri][3];
        *(float4*)&out[(size_t)(n0 + tr * 8 + ri) * 128 + tc * 4] = o;
    }
}

// ---------------------------------------------------------------------------
// depthwise 3x3x3 conv, pad 1
__global__ __launch_bounds__(256) void k_dw(
    const float* __restrict__ in, const float* __restrict__ w, const float* __restrict__ b,
    float* __restrict__ out)
{
    int idx = blockIdx.x * 256 + threadIdx.x;
    int n = idx >> 7;
    int c = idx & 127;
    int i = n / SWD; int rem = n - i * SWD;
    int j = rem / SD; int k = rem - j * SD;
    float acc = b[c];
    #pragma unroll
    for (int di = -1; di <= 1; ++di) {
        int ii = i + di;
        if (ii < 0 || ii >= SD) continue;
        #pragma unroll
        for (int dj = -1; dj <= 1; ++dj) {
            int jj = j + dj;
            if (jj < 0 || jj >= SD) continue;
            #pragma unroll
            for (int dk = -1; dk <= 1; ++dk) {
                int kk = k + dk;
                if (kk < 0 || kk >= SD) continue;
                acc = fmaf(w[c * 27 + ((di + 1) * 3 + (dj + 1)) * 3 + (dk + 1)],
                           in[(size_t)((ii * SD + jj) * SD + kk) * 128 + c], acc);
            }
        }
    }
    out[idx] = acc;
}

// ---------------------------------------------------------------------------
// shift-D + fc3 + GELU(exact) + residual(t) + LN(gn,bn) + transposed store
__global__ __launch_bounds__(256) void k_final(
    const float* __restrict__ in, const float* __restrict__ wT, const float* __restrict__ bias,
    const float* __restrict__ tin, const float* __restrict__ gn, const float* __restrict__ bn,
    float* __restrict__ out)
{
    __shared__ float SH[64 * 130];   // At (stride 128) then Res (stride 130)
    __shared__ float P1[4][64], P2[4][64], Mrow[64], Rrow[64];
    const int tid = threadIdx.x;
    const int n0 = blockIdx.x * 64;

    for (int idx = tid; idx < 64 * 128; idx += 256) {
        int c = idx & 127;
        int n = n0 + (idx >> 7);
        int g = c / 26;
        int s = g - 2;
        int coord = n % SD;
        int src = n - s;
        int cs = coord - s;
        float v = (cs >= 0 && cs < SD) ? in[(size_t)src * 128 + c] : 0.f;
        SH[idx] = v;
    }
    __syncthreads();

    const int tc = tid & 31;
    const int tr = tid >> 5;
    float acc[8][4];
    {
        float4 bb = *(const float4*)&bias[tc * 4];
        #pragma unroll
        for (int ri = 0; ri < 8; ++ri) {
            acc[ri][0] = bb.x; acc[ri][1] = bb.y; acc[ri][2] = bb.z; acc[ri][3] = bb.w;
        }
    }
    for (int k4 = 0; k4 < 32; ++k4) {
        float4 a[8];
        #pragma unroll
        for (int ri = 0; ri < 8; ++ri)
            a[ri] = *(const float4*)&SH[(tr * 8 + ri) * 128 + k4 * 4];
        #pragma unroll
        for (int kk = 0; kk < 4; ++kk) {
            float4 w = *(const float4*)&wT[(k4 * 4 + kk) * 128 + tc * 4];
            #pragma unroll
            for (int ri = 0; ri < 8; ++ri) {
                float av = ((const float*)&a[ri])[kk];
                acc[ri][0] = fmaf(av, w.x, acc[ri][0]);
                acc[ri][1] = fmaf(av, w.y, acc[ri][1]);
                acc[ri][2] = fmaf(av, w.z, acc[ri][2]);
                acc[ri][3] = fmaf(av, w.w, acc[ri][3]);
            }
        }
    }
    __syncthreads();   // done reading At region

    // GELU + residual -> Res (stride 130)
    #pragma unroll
    for (int ri = 0; ri < 8; ++ri) {
        int rr = tr * 8 + ri;
        float4 tt = *(const float4*)&tin[(size_t)(n0 + rr) * 128 + tc * 4];
        #pragma unroll
        for (int cj = 0; cj < 4; ++cj) {
            float hv = acc[ri][cj];
            float ge = 0.5f * hv * (1.f + erff(hv * 0.70710678118654752f));
            SH[rr * 130 + tc * 4 + cj] = ge + ((const float*)&tt)[cj];
        }
    }
    __syncthreads();

    {
        const int r = tid & 63;
        const int cg = tid >> 6;
        float s1 = 0.f, s2 = 0.f;
        #pragma unroll
        for (int m = 0; m < 32; ++m) {
            float v = SH[r * 130 + cg * 32 + m];
            s1 += v; s2 += v * v;
        }
        P1[cg][r] = s1; P2[cg][r] = s2;
    }
    __syncthreads();
    if (tid < 64) {
        float a = P1[0][tid] + P1[1][tid] + P1[2][tid] + P1[3][tid];
        float b = P2[0][tid] + P2[1][tid] + P2[2][tid] + P2[3][tid];
        float mean = a * (1.f / 128.f);
        float var = fmaxf(b * (1.f / 128.f) - mean * mean, 0.f);
        Mrow[tid] = mean;
        Rrow[tid] = rsqrtf(var + 1e-5f);
    }
    __syncthreads();
    // normalized, transposed write: out[c*NTOT + n]
    {
        const int r = tid & 63;
        const int cg = tid >> 6;
        float mean = Mrow[r], rstd = Rrow[r];
        #pragma unroll
        for (int m = 0; m < 32; ++m) {
            int c = cg * 32 + m;
            float v = (SH[r * 130 + c] - mean) * rstd * gn[c] + bn[c];
            out[(size_t)c * NTOT + n0 + r] = v;
        }
    }
}

// ---------------------------------------------------------------------------
extern "C" void kernel_launch(void* const* d_in, const int* in_sizes, int n_in,
                              void* d_out, int out_size, void* d_ws, size_t ws_size,
                              hipStream_t stream)
{
    const float* x    = (const float*)d_in[0];
    const float* pw   = (const float*)d_in[1];
    const float* pb   = (const float*)d_in[2];
    const float* g0   = (const float*)d_in[3];
    const float* b0   = (const float*)d_in[4];
    const float* g2   = (const float*)d_in[5];
    const float* b2   = (const float*)d_in[6];
    const float* fc1w = (const float*)d_in[7];
    const float* fc1b = (const float*)d_in[8];
    const float* dw1w = (const float*)d_in[9];
    const float* dw1b = (const float*)d_in[10];
    const float* fc2w = (const float*)d_in[11];
    const float* fc2b = (const float*)d_in[12];
    const float* dw2w = (const float*)d_in[13];
    const float* dw2b = (const float*)d_in[14];
    const float* fc3w = (const float*)d_in[15];
    const float* fc3b = (const float*)d_in[16];
    const float* gn   = (const float*)d_in[17];
    const float* bn   = (const float*)d_in[18];
    float* out = (float*)d_out;

    float* ws   = (float*)d_ws;
    float* tbuf = ws;                          // NTOT*128
    float* hbuf = ws + (size_t)NTOT * 128;     // NTOT*128
    float* pwT  = ws + (size_t)2 * NTOT * 128; // 108*128
    float* w1T  = pwT + 108 * 128;
    float* w2T  = w1T + 128 * 128;
    float* w3T  = w2T + 128 * 128;

    k_transpose_w<<<54, 256, 0, stream>>>(pw, pwT, 108);
    k_transpose_w<<<64, 256, 0, stream>>>(fc1w, w1T, 128);
    k_transpose_w<<<64, 256, 0, stream>>>(fc2w, w2T, 128);
    k_transpose_w<<<64, 256, 0, stream>>>(fc3w, w3T, 128);

    k_proj_ln<<<NTOT / 64, 256, 0, stream>>>(x, pwT, pb, g0, b0, g2, b2, tbuf, hbuf);
    k_shift_mm<0><<<NTOT / 64, 256, 0, stream>>>(hbuf, w1T, fc1b, out);
    k_dw<<<NTOT * 128 / 256, 256, 0, stream>>>(out, dw1w, dw1b, hbuf);
    k_shift_mm<1><<<NTOT / 64, 256, 0, stream>>>(hbuf, w2T, fc2b, out);
    k_dw<<<NTOT * 128 / 256, 256, 0, stream>>>(out, dw2w, dw2b, hbuf);
    k_final<<<NTOT / 64, 256, 0, stream>>>(hbuf, w3T, fc3b, tbuf, gn, bn, out);
}

// Round 2
// 440.531 us; speedup vs baseline: 2.3944x; 2.3944x over previous
//
#include <hip/hip_runtime.h>
#include <math.h>

#define NTOT 110592   // 48^3
#define SD 48
#define SWD 2304      // 48*48

// ---------------------------------------------------------------------------
// transpose weights: dst[k*128+co] = src[co*K + k]
__global__ __launch_bounds__(256) void k_transpose_w(const float* __restrict__ src,
                                                     float* __restrict__ dst, int K) {
    int idx = blockIdx.x * 256 + threadIdx.x;
    if (idx >= K * 128) return;
    int k = idx >> 7;
    int co = idx & 127;
    dst[idx] = src[co * K + k];
}

// ---------------------------------------------------------------------------
// proj conv (im2col matmul, K=108) + LN(g0,b0) -> t, + LN(g2,b2) -> h
__global__ __launch_bounds__(256) void k_proj_ln(
    const float* __restrict__ x, const float* __restrict__ pwT, const float* __restrict__ pb,
    const float* __restrict__ g0, const float* __restrict__ b0,
    const float* __restrict__ g2, const float* __restrict__ b2,
    float* __restrict__ t_out, float* __restrict__ h_out)
{
    __shared__ float SH[64 * 130];      // used as At (stride 112) then Res (stride 130)
    __shared__ float P1[4][64], P2[4][64], Mrow[64], Rrow[64];
    const int tid = threadIdx.x;
    const int n0 = blockIdx.x * 64;

    // im2col staging: At(r,m) = SH[r*112+m], m in [0,108)
    for (int idx = tid; idx < 64 * 108; idx += 256) {
        int r = idx / 108;
        int m = idx - r * 108;
        int ci = m / 27;  int mm = m - ci * 27;
        int ti = mm / 9;  int mj = mm - ti * 9;
        int tj = mj / 3;  int tk = mj - tj * 3;
        int n = n0 + r;
        int oi = n / SWD; int rem = n - oi * SWD;
        int oj = rem / SD; int ok = rem - oj * SD;
        int ii = 2 * oi + ti - 1;
        int ij = 2 * oj + tj - 1;
        int ik = 2 * ok + tk - 1;
        float v = 0.f;
        if (ii >= 0 && ii < 96 && ij >= 0 && ij < 96 && ik >= 0 && ik < 96)
            v = x[((ci * 96 + ii) * 96 + ij) * 96 + ik];
        SH[r * 112 + m] = v;
    }
    __syncthreads();

    const int tc = tid & 31;
    const int tr = tid >> 5;   // 0..7 -> rows tr*8..tr*8+7
    float acc[8][4];
    {
        float4 bb = *(const float4*)&pb[tc * 4];
        #pragma unroll
        for (int ri = 0; ri < 8; ++ri) {
            acc[ri][0] = bb.x; acc[ri][1] = bb.y; acc[ri][2] = bb.z; acc[ri][3] = bb.w;
        }
    }
    for (int k4 = 0; k4 < 27; ++k4) {
        float4 a[8];
        #pragma unroll
        for (int ri = 0; ri < 8; ++ri)
            a[ri] = *(const float4*)&SH[(tr * 8 + ri) * 112 + k4 * 4];
        #pragma unroll
        for (int kk = 0; kk < 4; ++kk) {
            float4 w = *(const float4*)&pwT[(k4 * 4 + kk) * 128 + tc * 4];
            #pragma unroll
            for (int ri = 0; ri < 8; ++ri) {
                float av = ((const float*)&a[ri])[kk];
                acc[ri][0] = fmaf(av, w.x, acc[ri][0]);
                acc[ri][1] = fmaf(av, w.y, acc[ri][1]);
                acc[ri][2] = fmaf(av, w.z, acc[ri][2]);
                acc[ri][3] = fmaf(av, w.w, acc[ri][3]);
            }
        }
    }
    __syncthreads();   // done reading At region

    // store conv result into Res (stride 130)
    #pragma unroll
    for (int ri = 0; ri < 8; ++ri)
        #pragma unroll
        for (int cj = 0; cj < 4; ++cj)
            SH[(tr * 8 + ri) * 130 + tc * 4 + cj] = acc[ri][cj];
    __syncthreads();

    // LN0 stats
    {
        const int r = tid & 63;
        const int cg = tid >> 6;
        float s1 = 0.f, s2 = 0.f;
        #pragma unroll
        for (int m = 0; m < 32; ++m) {
            float v = SH[r * 130 + cg * 32 + m];
            s1 += v; s2 += v * v;
        }
        P1[cg][r] = s1; P2[cg][r] = s2;
    }
    __syncthreads();
    if (tid < 64) {
        float a = P1[0][tid] + P1[1][tid] + P1[2][tid] + P1[3][tid];
        float b = P2[0][tid] + P2[1][tid] + P2[2][tid] + P2[3][tid];
        float mean = a * (1.f / 128.f);
        float var = fmaxf(b * (1.f / 128.f) - mean * mean, 0.f);
        Mrow[tid] = mean;
        Rrow[tid] = rsqrtf(var + 1e-5f);
    }
    __syncthreads();
    // apply LN0 -> t (in place), accumulate LN2 stats
    {
        const int r = tid & 63;
        const int cg = tid >> 6;
        float mean = Mrow[r], rstd = Rrow[r];
        float s1 = 0.f, s2 = 0.f;
        #pragma unroll
        for (int m = 0; m < 32; ++m) {
            int c = cg * 32 + m;
            float z = (SH[r * 130 + c] - mean) * rstd;
            float tv = z * g0[c] + b0[c];
            SH[r * 130 + c] = tv;
            s1 += tv; s2 += tv * tv;
        }
        P1[cg][r] = s1; P2[cg][r] = s2;
    }
    __syncthreads();
    if (tid < 64) {
        float a = P1[0][tid] + P1[1][tid] + P1[2][tid] + P1[3][tid];
        float b = P2[0][tid] + P2[1][tid] + P2[2][tid] + P2[3][tid];
        float mean = a * (1.f / 128.f);
        float var = fmaxf(b * (1.f / 128.f) - mean * mean, 0.f);
        Mrow[tid] = mean;
        Rrow[tid] = rsqrtf(var + 1e-5f);
    }
    __syncthreads();
    // write t and h (coalesced)
    {
        const int c = tid & 127;
        const int rh = tid >> 7;    // 0..1
        float gg = g2[c], bb2 = b2[c];
        for (int rr = rh; rr < 64; rr += 2) {
            float tv = SH[rr * 130 + c];
            t_out[(size_t)(n0 + rr) * 128 + c] = tv;
            float hv = (tv - Mrow[rr]) * Rrow[rr] * gg + bb2;
            h_out[(size_t)(n0 + rr) * 128 + c] = hv;
        }
    }
}

// ---------------------------------------------------------------------------
// axial shift (fused into A gather) + matmul (out = shift(in) @ W^T + b)
// AXIS: 0 -> H (stride 2304), 1 -> W (stride 48), 2 -> D (stride 1)
template <int AXIS>
__global__ __launch_bounds__(256) void k_shift_mm(
    const float* __restrict__ in, const float* __restrict__ wT, const float* __restrict__ bias,
    float* __restrict__ out)
{
    __shared__ float At[64 * 128];
    const int tid = threadIdx.x;
    const int n0 = blockIdx.x * 64;

    for (int idx = tid; idx < 64 * 128; idx += 256) {
        int c = idx & 127;
        int n = n0 + (idx >> 7);
        int g = c / 26;
        int s = g - 2;
        int coord, src;
        if (AXIS == 0)      { coord = n / SWD;        src = n - s * SWD; }
        else if (AXIS == 1) { coord = (n / SD) % SD;  src = n - s * SD;  }
        else                { coord = n % SD;         src = n - s;       }
        int cs = coord - s;
        float v = (cs >= 0 && cs < SD) ? in[(size_t)src * 128 + c] : 0.f;
        At[idx] = v;
    }
    __syncthreads();

    const int tc = tid & 31;
    const int tr = tid >> 5;
    float acc[8][4];
    {
        float4 bb = *(const float4*)&bias[tc * 4];
        #pragma unroll
        for (int ri = 0; ri < 8; ++ri) {
            acc[ri][0] = bb.x; acc[ri][1] = bb.y; acc[ri][2] = bb.z; acc[ri][3] = bb.w;
        }
    }
    for (int k4 = 0; k4 < 32; ++k4) {
        float4 a[8];
        #pragma unroll
        for (int ri = 0; ri < 8; ++ri)
            a[ri] = *(const float4*)&At[(tr * 8 + ri) * 128 + k4 * 4];
        #pragma unroll
        for (int kk = 0; kk < 4; ++kk) {
            float4 w = *(const float4*)&wT[(k4 * 4 + kk) * 128 + tc * 4];
            #pragma unroll
            for (int ri = 0; ri < 8; ++ri) {
                float av = ((const float*)&a[ri])[kk];
                acc[ri][0] = fmaf(av, w.x, acc[ri][0]);
                acc[ri][1] = fmaf(av, w.y, acc[ri][1]);
                acc[ri][2] = fmaf(av, w.z, acc[ri][2]);
                acc[ri][3] = fmaf(av, w.w, acc[ri][3]);
            }
        }
    }
    #pragma unroll
    for (int ri = 0; ri < 8; ++ri) {
        float4 o;
        o.x = acc[ri][0]; o.y = acc[ri][1]; o.z = acc[ri][2]; o.w = acc[ri][3];
        *(float4*)&out[(size_t)(n0 + tr * 8 + ri) * 128 + tc * 4] = o;
    }
}

// ---------------------------------------------------------------------------
// depthwise 3x3x3 conv, pad 1 — register-blocked sliding window.
// Block = one (i,j) column (grid SWD). Thread: 4 channels (float4) x 6 k's.
// wt is pre-transposed: wt[tap*128 + c], tap = (di+1)*9 + (dj+1)*3 + dk.
__global__ __launch_bounds__(256) void k_dw(
    const float* __restrict__ in, const float* __restrict__ wt, const float* __restrict__ b,
    float* __restrict__ out)
{
    const int tid = threadIdx.x;
    const int cg = tid & 31;      // channel group -> c = cg*4
    const int kq = tid >> 5;      // 0..7
    const int k0 = kq * 6;        // this thread's 6 outputs: k0..k0+5
    const int ij = blockIdx.x;    // 0..2303
    const int i = ij / SD;
    const int j = ij - i * SD;
    const int c = cg * 4;

    float4 acc[6];
    {
        float4 bb = *(const float4*)&b[c];
        #pragma unroll
        for (int t = 0; t < 6; ++t) acc[t] = bb;
    }

    #pragma unroll
    for (int di = -1; di <= 1; ++di) {
        int ii = i + di;
        if (ii < 0 || ii >= SD) continue;          // block-uniform branch
        #pragma unroll
        for (int dj = -1; dj <= 1; ++dj) {
            int jj = j + dj;
            if (jj < 0 || jj >= SD) continue;      // block-uniform branch
            const float* base = &in[(size_t)((ii * SD + jj) * SD) * 128 + c];
            const int tap0 = ((di + 1) * 3 + (dj + 1)) * 3;
            float4 wv[3];
            #pragma unroll
            for (int dk = 0; dk < 3; ++dk)
                wv[dk] = *(const float4*)&wt[(tap0 + dk) * 128 + c];
            // sliding window: v[s] = input at k = k0 + s - 1
            float4 v[8];
            #pragma unroll
            for (int s = 0; s < 8; ++s) {
                int kk = k0 + s - 1;
                if (kk >= 0 && kk < SD)
                    v[s] = *(const float4*)(base + (size_t)kk * 128);
                else
                    v[s] = make_float4(0.f, 0.f, 0.f, 0.f);
            }
            #pragma unroll
            for (int t = 0; t < 6; ++t) {
                #pragma unroll
                for (int dk = 0; dk < 3; ++dk) {
                    float4 vv = v[t + dk];
                    acc[t].x = fmaf(wv[dk].x, vv.x, acc[t].x);
                    acc[t].y = fmaf(wv[dk].y, vv.y, acc[t].y);
                    acc[t].z = fmaf(wv[dk].z, vv.z, acc[t].z);
                    acc[t].w = fmaf(wv[dk].w, vv.w, acc[t].w);
                }
            }
        }
    }
    const size_t nbase = (size_t)((i * SD + j) * SD + k0) * 128 + c;
    #pragma unroll
    for (int t = 0; t < 6; ++t)
        *(float4*)&out[nbase + (size_t)t * 128] = acc[t];
}

// ---------------------------------------------------------------------------
// shift-D + fc3 + GELU(exact) + residual(t) + LN(gn,bn) + transposed store
__global__ __launch_bounds__(256) void k_final(
    const float* __restrict__ in, const float* __restrict__ wT, const float* __restrict__ bias,
    const float* __restrict__ tin, const float* __restrict__ gn, const float* __restrict__ bn,
    float* __restrict__ out)
{
    __shared__ float SH[64 * 130];   // At (stride 128) then Res (stride 130)
    __shared__ float P1[4][64], P2[4][64], Mrow[64], Rrow[64];
    const int tid = threadIdx.x;
    const int n0 = blockIdx.x * 64;

    for (int idx = tid; idx < 64 * 128; idx += 256) {
        int c = idx & 127;
        int n = n0 + (idx >> 7);
        int g = c / 26;
        int s = g - 2;
        int coord = n % SD;
        int src = n - s;
        int cs = coord - s;
        float v = (cs >= 0 && cs < SD) ? in[(size_t)src * 128 + c] : 0.f;
        SH[idx] = v;
    }
    __syncthreads();

    const int tc = tid & 31;
    const int tr = tid >> 5;
    float acc[8][4];
    {
        float4 bb = *(const float4*)&bias[tc * 4];
        #pragma unroll
        for (int ri = 0; ri < 8; ++ri) {
            acc[ri][0] = bb.x; acc[ri][1] = bb.y; acc[ri][2] = bb.z; acc[ri][3] = bb.w;
        }
    }
    for (int k4 = 0; k4 < 32; ++k4) {
        float4 a[8];
        #pragma unroll
        for (int ri = 0; ri < 8; ++ri)
            a[ri] = *(const float4*)&SH[(tr * 8 + ri) * 128 + k4 * 4];
        #pragma unroll
        for (int kk = 0; kk < 4; ++kk) {
            float4 w = *(const float4*)&wT[(k4 * 4 + kk) * 128 + tc * 4];
            #pragma unroll
            for (int ri = 0; ri < 8; ++ri) {
                float av = ((const float*)&a[ri])[kk];
                acc[ri][0] = fmaf(av, w.x, acc[ri][0]);
                acc[ri][1] = fmaf(av, w.y, acc[ri][1]);
                acc[ri][2] = fmaf(av, w.z, acc[ri][2]);
                acc[ri][3] = fmaf(av, w.w, acc[ri][3]);
            }
        }
    }
    __syncthreads();   // done reading At region

    // GELU + residual -> Res (stride 130)
    #pragma unroll
    for (int ri = 0; ri < 8; ++ri) {
        int rr = tr * 8 + ri;
        float4 tt = *(const float4*)&tin[(size_t)(n0 + rr) * 128 + tc * 4];
        #pragma unroll
        for (int cj = 0; cj < 4; ++cj) {
            float hv = acc[ri][cj];
            float ge = 0.5f * hv * (1.f + erff(hv * 0.70710678118654752f));
            SH[rr * 130 + tc * 4 + cj] = ge + ((const float*)&tt)[cj];
        }
    }
    __syncthreads();

    {
        const int r = tid & 63;
        const int cg = tid >> 6;
        float s1 = 0.f, s2 = 0.f;
        #pragma unroll
        for (int m = 0; m < 32; ++m) {
            float v = SH[r * 130 + cg * 32 + m];
            s1 += v; s2 += v * v;
        }
        P1[cg][r] = s1; P2[cg][r] = s2;
    }
    __syncthreads();
    if (tid < 64) {
        float a = P1[0][tid] + P1[1][tid] + P1[2][tid] + P1[3][tid];
        float b = P2[0][tid] + P2[1][tid] + P2[2][tid] + P2[3][tid];
        float mean = a * (1.f / 128.f);
        float var = fmaxf(b * (1.f / 128.f) - mean * mean, 0.f);
        Mrow[tid] = mean;
        Rrow[tid] = rsqrtf(var + 1e-5f);
    }
    __syncthreads();
    // normalized, transposed write: out[c*NTOT + n]
    {
        const int r = tid & 63;
        const int cg = tid >> 6;
        float mean = Mrow[r], rstd = Rrow[r];
        #pragma unroll
        for (int m = 0; m < 32; ++m) {
            int c = cg * 32 + m;
            float v = (SH[r * 130 + c] - mean) * rstd * gn[c] + bn[c];
            out[(size_t)c * NTOT + n0 + r] = v;
        }
    }
}

// ---------------------------------------------------------------------------
extern "C" void kernel_launch(void* const* d_in, const int* in_sizes, int n_in,
                              void* d_out, int out_size, void* d_ws, size_t ws_size,
                              hipStream_t stream)
{
    const float* x    = (const float*)d_in[0];
    const float* pw   = (const float*)d_in[1];
    const float* pb   = (const float*)d_in[2];
    const float* g0   = (const float*)d_in[3];
    const float* b0   = (const float*)d_in[4];
    const float* g2   = (const float*)d_in[5];
    const float* b2   = (const float*)d_in[6];
    const float* fc1w = (const float*)d_in[7];
    const float* fc1b = (const float*)d_in[8];
    const float* dw1w = (const float*)d_in[9];
    const float* dw1b = (const float*)d_in[10];
    const float* fc2w = (const float*)d_in[11];
    const float* fc2b = (const float*)d_in[12];
    const float* dw2w = (const float*)d_in[13];
    const float* dw2b = (const float*)d_in[14];
    const float* fc3w = (const float*)d_in[15];
    const float* fc3b = (const float*)d_in[16];
    const float* gn   = (const float*)d_in[17];
    const float* bn   = (const float*)d_in[18];
    float* out = (float*)d_out;

    float* ws   = (float*)d_ws;
    float* tbuf = ws;                          // NTOT*128
    float* hbuf = ws + (size_t)NTOT * 128;     // NTOT*128
    float* pwT  = ws + (size_t)2 * NTOT * 128; // 108*128
    float* w1T  = pwT + 108 * 128;
    float* w2T  = w1T + 128 * 128;
    float* w3T  = w2T + 128 * 128;
    float* dwT1 = w3T + 128 * 128;             // 27*128
    float* dwT2 = dwT1 + 27 * 128;             // 27*128

    k_transpose_w<<<54, 256, 0, stream>>>(pw, pwT, 108);
    k_transpose_w<<<64, 256, 0, stream>>>(fc1w, w1T, 128);
    k_transpose_w<<<64, 256, 0, stream>>>(fc2w, w2T, 128);
    k_transpose_w<<<64, 256, 0, stream>>>(fc3w, w3T, 128);
    k_transpose_w<<<14, 256, 0, stream>>>(dw1w, dwT1, 27);
    k_transpose_w<<<14, 256, 0, stream>>>(dw2w, dwT2, 27);

    k_proj_ln<<<NTOT / 64, 256, 0, stream>>>(x, pwT, pb, g0, b0, g2, b2, tbuf, hbuf);
    k_shift_mm<0><<<NTOT / 64, 256, 0, stream>>>(hbuf, w1T, fc1b, out);
    k_dw<<<SWD, 256, 0, stream>>>(out, dwT1, dw1b, hbuf);
    k_shift_mm<1><<<NTOT / 64, 256, 0, stream>>>(hbuf, w2T, fc2b, out);
    k_dw<<<SWD, 256, 0, stream>>>(out, dwT2, dw2b, hbuf);
    k_final<<<NTOT / 64, 256, 0, stream>>>(hbuf, w3T, fc3b, tbuf, gn, bn, out);
}

// Round 3
// 306.581 us; speedup vs baseline: 3.4405x; 1.4369x over previous
//
#include <hip/hip_runtime.h>
#include <hip/hip_bf16.h>
#include <math.h>

#define NTOT 110592   // 48^3
#define SD 48
#define SWD 2304      // 48*48

typedef short s16x8 __attribute__((ext_vector_type(8)));
typedef unsigned short u16x8 __attribute__((ext_vector_type(8)));
typedef float f32x4 __attribute__((ext_vector_type(4)));
typedef unsigned short u16;

__device__ __forceinline__ float bf2f(u16 u) {
    unsigned int x = ((unsigned int)u) << 16;
    float f; __builtin_memcpy(&f, &x, 4); return f;
}
__device__ __forceinline__ u16 f2bf(float f) {
    __hip_bfloat16 h = __float2bfloat16(f);
    u16 u; __builtin_memcpy(&u, &h, 2); return u;
}

// ---------------------------------------------------------------------------
// transpose weights (f32): dst[k*128+co] = src[co*K + k]   (for depthwise w)
__global__ __launch_bounds__(256) void k_transpose_w(const float* __restrict__ src,
                                                     float* __restrict__ dst, int K) {
    int idx = blockIdx.x * 256 + threadIdx.x;
    if (idx >= K * 128) return;
    int k = idx >> 7;
    int co = idx & 127;
    dst[idx] = src[co * K + k];
}

// ---------------------------------------------------------------------------
// pack weights [128 co][K] into MFMA B-fragment layout (bf16), K padded to 128:
// dst[((t*4+s)*64 + lane)*8 + j] = w[16t+(lane&15)][32s + 8*(lane>>4) + j]
__global__ __launch_bounds__(256) void k_mkfrag(const float* __restrict__ src,
                                                u16* __restrict__ dst, int K) {
    int idx = blockIdx.x * 256 + threadIdx.x;   // [0, 2048)
    if (idx >= 2048) return;
    int lane = idx & 63;
    int s = (idx >> 6) & 3;
    int t = idx >> 8;
    int co = t * 16 + (lane & 15);
    int kb = s * 32 + (lane >> 4) * 8;
    #pragma unroll
    for (int j = 0; j < 8; ++j) {
        int k = kb + j;
        float v = (k < K) ? src[co * K + k] : 0.f;
        dst[idx * 8 + j] = f2bf(v);
    }
}

// ---------------------------------------------------------------------------
// proj conv (im2col MFMA, K=108 padded 128) + LN(g0,b0)->t(f32), LN(g2,b2)->h(bf16)
__global__ __launch_bounds__(256) void k_proj_ln(
    const float* __restrict__ x, const u16* __restrict__ wfrag, const float* __restrict__ pb,
    const float* __restrict__ g0, const float* __restrict__ b0,
    const float* __restrict__ g2, const float* __restrict__ b2,
    float* __restrict__ t_out, u16* __restrict__ h_out)
{
    __shared__ __align__(16) unsigned char smem[64 * 130 * 4];  // A(bf16,16KB) then SH(f32,stride130)
    __shared__ float P1[4][64], P2[4][64], Mrow[64], Rrow[64];
    float* SH = (float*)smem;
    const int tid = threadIdx.x;
    const int n0 = blockIdx.x * 64;

    // im2col staging -> swizzled bf16 LDS [64 rows][128 k] (k>=108 zero)
    for (int idx = tid; idx < 64 * 128; idx += 256) {
        int r = idx >> 7;
        int k = idx & 127;
        float v = 0.f;
        if (k < 108) {
            int ci = k / 27;  int mm = k - ci * 27;
            int ti = mm / 9;  int mj = mm - ti * 9;
            int tj = mj / 3;  int tk = mj - tj * 3;
            int n = n0 + r;
            int oi = n / SWD; int rem = n - oi * SWD;
            int oj = rem / SD; int ok = rem - oj * SD;
            int ii = 2 * oi + ti - 1;
            int ij = 2 * oj + tj - 1;
            int ik = 2 * ok + tk - 1;
            if (ii >= 0 && ii < 96 && ij >= 0 && ij < 96 && ik >= 0 && ik < 96)
                v = x[((ci * 96 + ii) * 96 + ij) * 96 + ik];
        }
        int byte = r * 256 + ((2 * k) ^ ((r & 7) << 4));
        *(u16*)(smem + byte) = f2bf(v);
    }
    __syncthreads();

    const int lane = tid & 63;
    const int wv = tid >> 6;
    const int rb = wv * 16;
    const int colb = lane & 15;
    const int rquad = (lane >> 4) * 4;
    const int arow = rb + colb;
    const int kg16 = (lane >> 4) * 16;
    const int aswz = (arow & 7) << 4;

    f32x4 acc[8];
    #pragma unroll
    for (int t = 0; t < 8; ++t) {
        float bb = pb[t * 16 + colb];
        acc[t][0] = bb; acc[t][1] = bb; acc[t][2] = bb; acc[t][3] = bb;
    }
    #pragma unroll
    for (int s = 0; s < 4; ++s) {
        s16x8 a = *(const s16x8*)(smem + arow * 256 + ((s * 64 + kg16) ^ aswz));
        #pragma unroll
        for (int t = 0; t < 8; ++t) {
            s16x8 b = *(const s16x8*)&wfrag[((t * 4 + s) * 64 + lane) * 8];
            acc[t] = __builtin_amdgcn_mfma_f32_16x16x32_bf16(a, b, acc[t], 0, 0, 0);
        }
    }
    __syncthreads();   // all waves done reading A region

    #pragma unroll
    for (int t = 0; t < 8; ++t) {
        int col = t * 16 + colb;
        #pragma unroll
        for (int r4 = 0; r4 < 4; ++r4)
            SH[(rb + rquad + r4) * 130 + col] = acc[t][r4];
    }
    __syncthreads();

    // LN0 stats
    {
        const int r = tid & 63;
        const int cg = tid >> 6;
        float s1 = 0.f, s2 = 0.f;
        #pragma unroll
        for (int m = 0; m < 32; ++m) {
            float v = SH[r * 130 + cg * 32 + m];
            s1 += v; s2 += v * v;
        }
        P1[cg][r] = s1; P2[cg][r] = s2;
    }
    __syncthreads();
    if (tid < 64) {
        float a = P1[0][tid] + P1[1][tid] + P1[2][tid] + P1[3][tid];
        float b = P2[0][tid] + P2[1][tid] + P2[2][tid] + P2[3][tid];
        float mean = a * (1.f / 128.f);
        float var = fmaxf(b * (1.f / 128.f) - mean * mean, 0.f);
        Mrow[tid] = mean;
        Rrow[tid] = rsqrtf(var + 1e-5f);
    }
    __syncthreads();
    // apply LN0 -> t (in place), accumulate LN2 stats
    {
        const int r = tid & 63;
        const int cg = tid >> 6;
        float mean = Mrow[r], rstd = Rrow[r];
        float s1 = 0.f, s2 = 0.f;
        #pragma unroll
        for (int m = 0; m < 32; ++m) {
            int c = cg * 32 + m;
            float z = (SH[r * 130 + c] - mean) * rstd;
            float tv = z * g0[c] + b0[c];
            SH[r * 130 + c] = tv;
            s1 += tv; s2 += tv * tv;
        }
        P1[cg][r] = s1; P2[cg][r] = s2;
    }
    __syncthreads();
    if (tid < 64) {
        float a = P1[0][tid] + P1[1][tid] + P1[2][tid] + P1[3][tid];
        float b = P2[0][tid] + P2[1][tid] + P2[2][tid] + P2[3][tid];
        float mean = a * (1.f / 128.f);
        float var = fmaxf(b * (1.f / 128.f) - mean * mean, 0.f);
        Mrow[tid] = mean;
        Rrow[tid] = rsqrtf(var + 1e-5f);
    }
    __syncthreads();
    {
        const int c = tid & 127;
        const int rh = tid >> 7;
        float gg = g2[c], bb2 = b2[c];
        for (int rr = rh; rr < 64; rr += 2) {
            float tv = SH[rr * 130 + c];
            t_out[(size_t)(n0 + rr) * 128 + c] = tv;
            float hv = (tv - Mrow[rr]) * Rrow[rr] * gg + bb2;
            h_out[(size_t)(n0 + rr) * 128 + c] = f2bf(hv);
        }
    }
}

// ---------------------------------------------------------------------------
// axial shift (fused gather) + MFMA matmul: out = shift(in) @ W^T + b   (bf16 io)
// AXIS: 0 -> H, 1 -> W, 2 -> D
template <int AXIS>
__global__ __launch_bounds__(256) void k_shift_mm(
    const u16* __restrict__ in, const u16* __restrict__ wfrag, const float* __restrict__ bias,
    u16* __restrict__ out)
{
    __shared__ __align__(16) unsigned char Asm[128 * 256];   // 128 rows x 128 bf16, swizzled
    const int tid = threadIdx.x;
    const int n0 = blockIdx.x * 128;

    for (int idx = tid; idx < 128 * 128; idx += 256) {
        int row = idx >> 7;
        int c = idx & 127;
        int n = n0 + row;
        int sh = c / 26 - 2;
        int coord, src;
        if (AXIS == 0)      { coord = n / SWD;        src = n - sh * SWD; }
        else if (AXIS == 1) { coord = (n / SD) % SD;  src = n - sh * SD;  }
        else                { coord = n % SD;         src = n - sh;       }
        int cs = coord - sh;
        u16 v = (cs >= 0 && cs < SD) ? in[(size_t)src * 128 + c] : (u16)0;
        int byte = row * 256 + ((2 * c) ^ ((row & 7) << 4));
        *(u16*)(Asm + byte) = v;
    }
    __syncthreads();

    const int lane = tid & 63;
    const int wv = tid >> 6;
    const int rb = wv * 32;
    const int colb = lane & 15;
    const int rquad = (lane >> 4) * 4;
    const int arow0 = rb + colb;
    const int arow1 = arow0 + 16;
    const int kg16 = (lane >> 4) * 16;
    const int aswz0 = (arow0 & 7) << 4;

    f32x4 acc[2][8];
    #pragma unroll
    for (int t = 0; t < 8; ++t) {
        float bb = bias[t * 16 + colb];
        acc[0][t][0] = bb; acc[0][t][1] = bb; acc[0][t][2] = bb; acc[0][t][3] = bb;
        acc[1][t] = acc[0][t];
    }
    #pragma unroll
    for (int s = 0; s < 4; ++s) {
        int kb = s * 64 + kg16;
        s16x8 a0 = *(const s16x8*)(Asm + arow0 * 256 + (kb ^ aswz0));
        s16x8 a1 = *(const s16x8*)(Asm + arow1 * 256 + (kb ^ aswz0));
        #pragma unroll
        for (int t = 0; t < 8; ++t) {
            s16x8 b = *(const s16x8*)&wfrag[((t * 4 + s) * 64 + lane) * 8];
            acc[0][t] = __builtin_amdgcn_mfma_f32_16x16x32_bf16(a0, b, acc[0][t], 0, 0, 0);
            acc[1][t] = __builtin_amdgcn_mfma_f32_16x16x32_bf16(a1, b, acc[1][t], 0, 0, 0);
        }
    }
    #pragma unroll
    for (int rt = 0; rt < 2; ++rt) {
        #pragma unroll
        for (int t = 0; t < 8; ++t) {
            int col = t * 16 + colb;
            #pragma unroll
            for (int r4 = 0; r4 < 4; ++r4) {
                int row = rb + rt * 16 + rquad + r4;
                out[(size_t)(n0 + row) * 128 + col] = f2bf(acc[rt][t][r4]);
            }
        }
    }
}

// ---------------------------------------------------------------------------
// depthwise 3x3x3 conv, bf16 io; wt f32 [27 taps][128 c]; thread: 8 ch x 3 k
__global__ __launch_bounds__(256) void k_dw(
    const u16* __restrict__ in, const float* __restrict__ wt, const float* __restrict__ b,
    u16* __restrict__ out)
{
    const int tid = threadIdx.x;
    const int cg = tid & 15;       // c = cg*8
    const int kq = tid >> 4;       // 0..15 -> k0 = kq*3
    const int k0 = kq * 3;
    const int ij = blockIdx.x;
    const int i = ij / SD;
    const int j = ij - i * SD;
    const int c = cg * 8;

    float acc[3][8];
    {
        float4 ba = *(const float4*)&b[c];
        float4 bb = *(const float4*)&b[c + 4];
        #pragma unroll
        for (int t = 0; t < 3; ++t) {
            acc[t][0] = ba.x; acc[t][1] = ba.y; acc[t][2] = ba.z; acc[t][3] = ba.w;
            acc[t][4] = bb.x; acc[t][5] = bb.y; acc[t][6] = bb.z; acc[t][7] = bb.w;
        }
    }

    #pragma unroll
    for (int di = -1; di <= 1; ++di) {
        int ii = i + di;
        if (ii < 0 || ii >= SD) continue;
        #pragma unroll
        for (int dj = -1; dj <= 1; ++dj) {
            int jj = j + dj;
            if (jj < 0 || jj >= SD) continue;
            const u16* base = &in[(size_t)((ii * SD + jj) * SD) * 128 + c];
            const int tap0 = ((di + 1) * 3 + (dj + 1)) * 3;
            float wv[3][8];
            #pragma unroll
            for (int dk = 0; dk < 3; ++dk) {
                float4 wa = *(const float4*)&wt[(tap0 + dk) * 128 + c];
                float4 wb = *(const float4*)&wt[(tap0 + dk) * 128 + c + 4];
                wv[dk][0] = wa.x; wv[dk][1] = wa.y; wv[dk][2] = wa.z; wv[dk][3] = wa.w;
                wv[dk][4] = wb.x; wv[dk][5] = wb.y; wv[dk][6] = wb.z; wv[dk][7] = wb.w;
            }
            float v[5][8];
            #pragma unroll
            for (int s = 0; s < 5; ++s) {
                int kk = k0 + s - 1;
                if (kk >= 0 && kk < SD) {
                    u16x8 u = *(const u16x8*)(base + (size_t)kk * 128);
                    #pragma unroll
                    for (int m = 0; m < 8; ++m) v[s][m] = bf2f(u[m]);
                } else {
                    #pragma unroll
                    for (int m = 0; m < 8; ++m) v[s][m] = 0.f;
                }
            }
            #pragma unroll
            for (int t = 0; t < 3; ++t)
                #pragma unroll
                for (int dk = 0; dk < 3; ++dk)
                    #pragma unroll
                    for (int m = 0; m < 8; ++m)
                        acc[t][m] = fmaf(wv[dk][m], v[t + dk][m], acc[t][m]);
        }
    }
    #pragma unroll
    for (int t = 0; t < 3; ++t) {
        u16x8 o;
        #pragma unroll
        for (int m = 0; m < 8; ++m) o[m] = f2bf(acc[t][m]);
        *(u16x8*)&out[(size_t)((i * SD + j) * SD + k0 + t) * 128 + c] = o;
    }
}

// ---------------------------------------------------------------------------
// shift-D + fc3 (MFMA) + GELU + residual(t) + LN(gn,bn) + transposed store
__global__ __launch_bounds__(256) void k_final(
    const u16* __restrict__ in, const u16* __restrict__ wfrag, const float* __restrict__ bias,
    const float* __restrict__ tin, const float* __restrict__ gn, const float* __restrict__ bn,
    float* __restrict__ out)
{
    __shared__ __align__(16) unsigned char smem[64 * 130 * 4];
    __shared__ float P1[4][64], P2[4][64], Mrow[64], Rrow[64];
    float* SH = (float*)smem;
    const int tid = threadIdx.x;
    const int n0 = blockIdx.x * 64;

    for (int idx = tid; idx < 64 * 128; idx += 256) {
        int row = idx >> 7;
        int c = idx & 127;
        int n = n0 + row;
        int sh = c / 26 - 2;
        int coord = n % SD;
        int src = n - sh;
        int cs = coord - sh;
        u16 v = (cs >= 0 && cs < SD) ? in[(size_t)src * 128 + c] : (u16)0;
        int byte = row * 256 + ((2 * c) ^ ((row & 7) << 4));
        *(u16*)(smem + byte) = v;
    }
    __syncthreads();

    const int lane = tid & 63;
    const int wv = tid >> 6;
    const int rb = wv * 16;
    const int colb = lane & 15;
    const int rquad = (lane >> 4) * 4;
    const int arow = rb + colb;
    const int kg16 = (lane >> 4) * 16;
    const int aswz = (arow & 7) << 4;

    f32x4 acc[8];
    #pragma unroll
    for (int t = 0; t < 8; ++t) {
        float bb = bias[t * 16 + colb];
        acc[t][0] = bb; acc[t][1] = bb; acc[t][2] = bb; acc[t][3] = bb;
    }
    #pragma unroll
    for (int s = 0; s < 4; ++s) {
        s16x8 a = *(const s16x8*)(smem + arow * 256 + ((s * 64 + kg16) ^ aswz));
        #pragma unroll
        for (int t = 0; t < 8; ++t) {
            s16x8 b = *(const s16x8*)&wfrag[((t * 4 + s) * 64 + lane) * 8];
            acc[t] = __builtin_amdgcn_mfma_f32_16x16x32_bf16(a, b, acc[t], 0, 0, 0);
        }
    }
    __syncthreads();   // done reading A region

    // GELU + residual dump
    #pragma unroll
    for (int t = 0; t < 8; ++t) {
        int col = t * 16 + colb;
        #pragma unroll
        for (int r4 = 0; r4 < 4; ++r4) {
            int row = rb + rquad + r4;
            float hv = acc[t][r4];
            float ge = 0.5f * hv * (1.f + erff(hv * 0.70710678118654752f));
            float tv = tin[(size_t)(n0 + row) * 128 + col];
            SH[row * 130 + col] = ge + tv;
        }
    }
    __syncthreads();

    {
        const int r = tid & 63;
        const int cg = tid >> 6;
        float s1 = 0.f, s2 = 0.f;
        #pragma unroll
        for (int m = 0; m < 32; ++m) {
            float v = SH[r * 130 + cg * 32 + m];
            s1 += v; s2 += v * v;
        }
        P1[cg][r] = s1; P2[cg][r] = s2;
    }
    __syncthreads();
    if (tid < 64) {
        float a = P1[0][tid] + P1[1][tid] + P1[2][tid] + P1[3][tid];
        float b = P2[0][tid] + P2[1][tid] + P2[2][tid] + P2[3][tid];
        float mean = a * (1.f / 128.f);
        float var = fmaxf(b * (1.f / 128.f) - mean * mean, 0.f);
        Mrow[tid] = mean;
        Rrow[tid] = rsqrtf(var + 1e-5f);
    }
    __syncthreads();
    {
        const int r = tid & 63;
        const int cg = tid >> 6;
        float mean = Mrow[r], rstd = Rrow[r];
        #pragma unroll
        for (int m = 0; m < 32; ++m) {
            int c = cg * 32 + m;
            float v = (SH[r * 130 + c] - mean) * rstd * gn[c] + bn[c];
            out[(size_t)c * NTOT + n0 + r] = v;
        }
    }
}

// ---------------------------------------------------------------------------
extern "C" void kernel_launch(void* const* d_in, const int* in_sizes, int n_in,
                              void* d_out, int out_size, void* d_ws, size_t ws_size,
                              hipStream_t stream)
{
    const float* x    = (const float*)d_in[0];
    const float* pw   = (const float*)d_in[1];
    const float* pb   = (const float*)d_in[2];
    const float* g0   = (const float*)d_in[3];
    const float* b0   = (const float*)d_in[4];
    const float* g2   = (const float*)d_in[5];
    const float* b2   = (const float*)d_in[6];
    const float* fc1w = (const float*)d_in[7];
    const float* fc1b = (const float*)d_in[8];
    const float* dw1w = (const float*)d_in[9];
    const float* dw1b = (const float*)d_in[10];
    const float* fc2w = (const float*)d_in[11];
    const float* fc2b = (const float*)d_in[12];
    const float* dw2w = (const float*)d_in[13];
    const float* dw2b = (const float*)d_in[14];
    const float* fc3w = (const float*)d_in[15];
    const float* fc3b = (const float*)d_in[16];
    const float* gn   = (const float*)d_in[17];
    const float* bn   = (const float*)d_in[18];
    float* out = (float*)d_out;

    char* wsb = (char*)d_ws;
    float* tbuf  = (float*)wsb;                                    // NTOT*128 f32
    u16*   h1    = (u16*)(wsb + (size_t)NTOT * 128 * 4);           // NTOT*128 bf16
    u16*   h2    = (u16*)((char*)h1 + (size_t)NTOT * 128 * 2);     // NTOT*128 bf16
    u16*   wfP   = (u16*)((char*)h2 + (size_t)NTOT * 128 * 2);     // 16384 u16 each
    u16*   wf1   = wfP + 16384;
    u16*   wf2   = wf1 + 16384;
    u16*   wf3   = wf2 + 16384;
    float* dwT1  = (float*)(wf3 + 16384);                          // 27*128 f32
    float* dwT2  = dwT1 + 27 * 128;

    k_mkfrag<<<8, 256, 0, stream>>>(pw, wfP, 108);
    k_mkfrag<<<8, 256, 0, stream>>>(fc1w, wf1, 128);
    k_mkfrag<<<8, 256, 0, stream>>>(fc2w, wf2, 128);
    k_mkfrag<<<8, 256, 0, stream>>>(fc3w, wf3, 128);
    k_transpose_w<<<14, 256, 0, stream>>>(dw1w, dwT1, 27);
    k_transpose_w<<<14, 256, 0, stream>>>(dw2w, dwT2, 27);

    k_proj_ln<<<NTOT / 64, 256, 0, stream>>>(x, wfP, pb, g0, b0, g2, b2, tbuf, h1);
    k_shift_mm<0><<<NTOT / 128, 256, 0, stream>>>(h1, wf1, fc1b, h2);
    k_dw<<<SWD, 256, 0, stream>>>(h2, dwT1, dw1b, h1);
    k_shift_mm<1><<<NTOT / 128, 256, 0, stream>>>(h1, wf2, fc2b, h2);
    k_dw<<<SWD, 256, 0, stream>>>(h2, dwT2, dw2b, h1);
    k_final<<<NTOT / 64, 256, 0, stream>>>(h1, wf3, fc3b, tbuf, gn, bn, out);
}

// Round 4
// 270.483 us; speedup vs baseline: 3.8997x; 1.1335x over previous
//
#include <hip/hip_runtime.h>
#include <hip/hip_bf16.h>
#include <math.h>

#define NTOT 110592   // 48^3
#define SD 48
#define SWD 2304      // 48*48

typedef short s16x8 __attribute__((ext_vector_type(8)));
typedef unsigned short u16x8 __attribute__((ext_vector_type(8)));
typedef float f32x4 __attribute__((ext_vector_type(4)));
typedef unsigned short u16;

__device__ __forceinline__ float bf2f(u16 u) {
    unsigned int x = ((unsigned int)u) << 16;
    float f; __builtin_memcpy(&f, &x, 4); return f;
}
__device__ __forceinline__ u16 f2bf(float f) {
    __hip_bfloat16 h = __float2bfloat16(f);
    u16 u; __builtin_memcpy(&u, &h, 2); return u;
}

// ---------------------------------------------------------------------------
// transpose weights (f32): dst[k*128+co] = src[co*K + k]   (for depthwise w)
__global__ __launch_bounds__(256) void k_transpose_w(const float* __restrict__ src,
                                                     float* __restrict__ dst, int K) {
    int idx = blockIdx.x * 256 + threadIdx.x;
    if (idx >= K * 128) return;
    int k = idx >> 7;
    int co = idx & 127;
    dst[idx] = src[co * K + k];
}

// ---------------------------------------------------------------------------
// pack weights [128 co][K] into MFMA fragment layout (bf16), K padded to 128:
// dst[((t*4+s)*64 + lane)*8 + j] = w[16t+(lane&15)][32s + 8*(lane>>4) + j]
__global__ __launch_bounds__(256) void k_mkfrag(const float* __restrict__ src,
                                                u16* __restrict__ dst, int K) {
    int idx = blockIdx.x * 256 + threadIdx.x;   // [0, 2048)
    if (idx >= 2048) return;
    int lane = idx & 63;
    int s = (idx >> 6) & 3;
    int t = idx >> 8;
    int co = t * 16 + (lane & 15);
    int kb = s * 32 + (lane >> 4) * 8;
    #pragma unroll
    for (int j = 0; j < 8; ++j) {
        int k = kb + j;
        float v = (k < K) ? src[co * K + k] : 0.f;
        dst[idx * 8 + j] = f2bf(v);
    }
}

// ---------------------------------------------------------------------------
// proj conv (im2col MFMA, K=108 pad 128) + LN0 -> t(bf16), LN2 -> h(bf16)
// LN stats fully in registers via 16-lane shfl butterflies.
__global__ __launch_bounds__(256) void k_proj_ln(
    const float* __restrict__ x, const u16* __restrict__ wfrag, const float* __restrict__ pb,
    const float* __restrict__ g0, const float* __restrict__ b0,
    const float* __restrict__ g2, const float* __restrict__ b2,
    u16* __restrict__ t_out, u16* __restrict__ h_out)
{
    __shared__ __align__(16) unsigned char smem[32768];   // A(16K) -> Tt(16K)+Th(16K)
    const int tid = threadIdx.x;
    const int n0 = blockIdx.x * 64;

    // im2col gather -> swizzled bf16 LDS [64 rows][128 k]
    for (int idx = tid; idx < 64 * 128; idx += 256) {
        int r = idx >> 7;
        int k = idx & 127;
        float v = 0.f;
        if (k < 108) {
            int ci = k / 27;  int mm = k - ci * 27;
            int ti = mm / 9;  int mj = mm - ti * 9;
            int tj = mj / 3;  int tk = mj - tj * 3;
            int n = n0 + r;
            int oi = n / SWD; int rem = n - oi * SWD;
            int oj = rem / SD; int ok = rem - oj * SD;
            int ii = 2 * oi + ti - 1;
            int ij = 2 * oj + tj - 1;
            int ik = 2 * ok + tk - 1;
            if (ii >= 0 && ii < 96 && ij >= 0 && ij < 96 && ik >= 0 && ik < 96)
                v = x[((ci * 96 + ii) * 96 + ij) * 96 + ik];
        }
        int byte = r * 256 + ((2 * k) ^ ((r & 7) << 4));
        *(u16*)(smem + byte) = f2bf(v);
    }
    __syncthreads();

    const int lane = tid & 63;
    const int wv = tid >> 6;
    const int rb = wv * 16;
    const int colb = lane & 15;
    const int q = lane >> 4;
    const int arow = rb + colb;
    const int aswz = (arow & 7) << 4;

    f32x4 acc[8];
    #pragma unroll
    for (int t = 0; t < 8; ++t) {
        float bb = pb[t * 16 + colb];
        acc[t][0] = bb; acc[t][1] = bb; acc[t][2] = bb; acc[t][3] = bb;
    }
    #pragma unroll
    for (int s = 0; s < 4; ++s) {
        s16x8 a = *(const s16x8*)(smem + arow * 256 + ((s * 64 + q * 16) ^ aswz));
        #pragma unroll
        for (int t = 0; t < 8; ++t) {
            s16x8 b = *(const s16x8*)&wfrag[((t * 4 + s) * 64 + lane) * 8];
            acc[t] = __builtin_amdgcn_mfma_f32_16x16x32_bf16(a, b, acc[t], 0, 0, 0);
        }
    }

    // LN0 stats in regs (sum over 8 col-tiles, then 16-lane butterfly)
    float s1[4] = {0.f,0.f,0.f,0.f}, s2[4] = {0.f,0.f,0.f,0.f};
    #pragma unroll
    for (int t = 0; t < 8; ++t)
        #pragma unroll
        for (int r4 = 0; r4 < 4; ++r4) {
            float v = acc[t][r4];
            s1[r4] += v; s2[r4] += v * v;
        }
    #pragma unroll
    for (int r4 = 0; r4 < 4; ++r4)
        #pragma unroll
        for (int m = 1; m < 16; m <<= 1) {
            s1[r4] += __shfl_xor(s1[r4], m);
            s2[r4] += __shfl_xor(s2[r4], m);
        }

    float g0v[8], b0v[8], g2v[8], b2v[8];
    #pragma unroll
    for (int t = 0; t < 8; ++t) {
        int c = t * 16 + colb;
        g0v[t] = g0[c]; b0v[t] = b0[c]; g2v[t] = g2[c]; b2v[t] = b2[c];
    }

    float tval[8][4];
    float u1[4] = {0.f,0.f,0.f,0.f}, u2[4] = {0.f,0.f,0.f,0.f};
    #pragma unroll
    for (int r4 = 0; r4 < 4; ++r4) {
        float mean = s1[r4] * (1.f / 128.f);
        float var  = fmaxf(s2[r4] * (1.f / 128.f) - mean * mean, 0.f);
        float rstd = rsqrtf(var + 1e-5f);
        #pragma unroll
        for (int t = 0; t < 8; ++t) {
            float tv = (acc[t][r4] - mean) * rstd * g0v[t] + b0v[t];
            tval[t][r4] = tv;
            u1[r4] += tv; u2[r4] += tv * tv;
        }
    }
    #pragma unroll
    for (int r4 = 0; r4 < 4; ++r4)
        #pragma unroll
        for (int m = 1; m < 16; m <<= 1) {
            u1[r4] += __shfl_xor(u1[r4], m);
            u2[r4] += __shfl_xor(u2[r4], m);
        }
    __syncthreads();   // A dead; reuse LDS for t/h dumps

    #pragma unroll
    for (int r4 = 0; r4 < 4; ++r4) {
        float mean2 = u1[r4] * (1.f / 128.f);
        float var2  = fmaxf(u2[r4] * (1.f / 128.f) - mean2 * mean2, 0.f);
        float rstd2 = rsqrtf(var2 + 1e-5f);
        int row = rb + q * 4 + r4;
        int rsw = (row & 7) << 4;
        #pragma unroll
        for (int t = 0; t < 8; ++t) {
            int col = t * 16 + colb;
            float tv = tval[t][r4];
            float hv = (tv - mean2) * rstd2 * g2v[t] + b2v[t];
            int off = (2 * col) ^ rsw;
            *(u16*)(smem + row * 256 + off)         = f2bf(tv);
            *(u16*)(smem + 16384 + row * 256 + off) = f2bf(hv);
        }
    }
    __syncthreads();
    for (int i = tid; i < 1024; i += 256) {
        int row = i >> 4;
        int c8 = (i & 15) * 8;
        int byte = row * 256 + ((2 * c8) ^ ((row & 7) << 4));
        *(u16x8*)&t_out[(size_t)(n0 + row) * 128 + c8] = *(const u16x8*)(smem + byte);
        *(u16x8*)&h_out[(size_t)(n0 + row) * 128 + c8] = *(const u16x8*)(smem + 16384 + byte);
    }
}

// ---------------------------------------------------------------------------
// axial shift (u32 pair-gather) + MFMA matmul + LDS-staged coalesced store
template <int AXIS>
__global__ __launch_bounds__(256) void k_shift_mm(
    const u16* __restrict__ in, const u16* __restrict__ wfrag, const float* __restrict__ bias,
    u16* __restrict__ out)
{
    __shared__ __align__(16) unsigned char Asm[128 * 256];
    const int tid = threadIdx.x;
    const int n0 = blockIdx.x * 128;

    // gather: channel pairs share shift group (boundaries 26/52/78/104 all even)
    for (int i = tid; i < 128 * 64; i += 256) {
        int row = i >> 6;
        int p = i & 63;
        int c = 2 * p;
        int n = n0 + row;
        int sh = c / 26 - 2;
        int coord, src;
        if (AXIS == 0)      { coord = n / SWD;        src = n - sh * SWD; }
        else if (AXIS == 1) { coord = (n / SD) % SD;  src = n - sh * SD;  }
        else                { coord = n % SD;         src = n - sh;       }
        int cs = coord - sh;
        unsigned v = 0;
        if (cs >= 0 && cs < SD) v = *(const unsigned*)&in[(size_t)src * 128 + c];
        *(unsigned*)(Asm + row * 256 + ((4 * p) ^ ((row & 7) << 4))) = v;
    }
    __syncthreads();

    const int lane = tid & 63;
    const int wv = tid >> 6;
    const int rb = wv * 32;
    const int colb = lane & 15;
    const int q = lane >> 4;
    const int arow0 = rb + colb;
    const int arow1 = arow0 + 16;
    const int aswz0 = (arow0 & 7) << 4;   // == arow1 swizzle (16 ≡ 0 mod 8)

    f32x4 acc[2][8];
    #pragma unroll
    for (int t = 0; t < 8; ++t) {
        float bb = bias[t * 16 + colb];
        acc[0][t][0] = bb; acc[0][t][1] = bb; acc[0][t][2] = bb; acc[0][t][3] = bb;
        acc[1][t] = acc[0][t];
    }
    #pragma unroll
    for (int s = 0; s < 4; ++s) {
        int kb = s * 64 + q * 16;
        s16x8 a0 = *(const s16x8*)(Asm + arow0 * 256 + (kb ^ aswz0));
        s16x8 a1 = *(const s16x8*)(Asm + arow1 * 256 + (kb ^ aswz0));
        #pragma unroll
        for (int t = 0; t < 8; ++t) {
            s16x8 b = *(const s16x8*)&wfrag[((t * 4 + s) * 64 + lane) * 8];
            acc[0][t] = __builtin_amdgcn_mfma_f32_16x16x32_bf16(a0, b, acc[0][t], 0, 0, 0);
            acc[1][t] = __builtin_amdgcn_mfma_f32_16x16x32_bf16(a1, b, acc[1][t], 0, 0, 0);
        }
    }
    __syncthreads();   // A dead; reuse for output staging

    #pragma unroll
    for (int rt = 0; rt < 2; ++rt)
        #pragma unroll
        for (int r4 = 0; r4 < 4; ++r4) {
            int row = rb + rt * 16 + q * 4 + r4;
            int rsw = (row & 7) << 4;
            #pragma unroll
            for (int t = 0; t < 8; ++t) {
                int col = t * 16 + colb;
                *(u16*)(Asm + row * 256 + ((2 * col) ^ rsw)) = f2bf(acc[rt][t][r4]);
            }
        }
    __syncthreads();
    for (int i = tid; i < 2048; i += 256) {
        int row = i >> 4;
        int c8 = (i & 15) * 8;
        *(u16x8*)&out[(size_t)(n0 + row) * 128 + c8] =
            *(const u16x8*)(Asm + row * 256 + ((2 * c8) ^ ((row & 7) << 4)));
    }
}

// ---------------------------------------------------------------------------
// depthwise 3x3x3 conv, bf16 io; wt f32 [27 taps][128 c]; thread: 8 ch x 3 k
__global__ __launch_bounds__(256) void k_dw(
    const u16* __restrict__ in, const float* __restrict__ wt, const float* __restrict__ b,
    u16* __restrict__ out)
{
    const int tid = threadIdx.x;
    const int cg = tid & 15;       // c = cg*8
    const int kq = tid >> 4;       // 0..15 -> k0 = kq*3
    const int k0 = kq * 3;
    const int ij = blockIdx.x;
    const int i = ij / SD;
    const int j = ij - i * SD;
    const int c = cg * 8;

    float acc[3][8];
    {
        float4 ba = *(const float4*)&b[c];
        float4 bb = *(const float4*)&b[c + 4];
        #pragma unroll
        for (int t = 0; t < 3; ++t) {
            acc[t][0] = ba.x; acc[t][1] = ba.y; acc[t][2] = ba.z; acc[t][3] = ba.w;
            acc[t][4] = bb.x; acc[t][5] = bb.y; acc[t][6] = bb.z; acc[t][7] = bb.w;
        }
    }

    #pragma unroll
    for (int di = -1; di <= 1; ++di) {
        int ii = i + di;
        if (ii < 0 || ii >= SD) continue;
        #pragma unroll
        for (int dj = -1; dj <= 1; ++dj) {
            int jj = j + dj;
            if (jj < 0 || jj >= SD) continue;
            const u16* base = &in[(size_t)((ii * SD + jj) * SD) * 128 + c];
            const int tap0 = ((di + 1) * 3 + (dj + 1)) * 3;
            float wv[3][8];
            #pragma unroll
            for (int dk = 0; dk < 3; ++dk) {
                float4 wa = *(const float4*)&wt[(tap0 + dk) * 128 + c];
                float4 wb = *(const float4*)&wt[(tap0 + dk) * 128 + c + 4];
                wv[dk][0] = wa.x; wv[dk][1] = wa.y; wv[dk][2] = wa.z; wv[dk][3] = wa.w;
                wv[dk][4] = wb.x; wv[dk][5] = wb.y; wv[dk][6] = wb.z; wv[dk][7] = wb.w;
            }
            float v[5][8];
            #pragma unroll
            for (int s = 0; s < 5; ++s) {
                int kk = k0 + s - 1;
                if (kk >= 0 && kk < SD) {
                    u16x8 u = *(const u16x8*)(base + (size_t)kk * 128);
                    #pragma unroll
                    for (int m = 0; m < 8; ++m) v[s][m] = bf2f(u[m]);
                } else {
                    #pragma unroll
                    for (int m = 0; m < 8; ++m) v[s][m] = 0.f;
                }
            }
            #pragma unroll
            for (int t = 0; t < 3; ++t)
                #pragma unroll
                for (int dk = 0; dk < 3; ++dk)
                    #pragma unroll
                    for (int m = 0; m < 8; ++m)
                        acc[t][m] = fmaf(wv[dk][m], v[t + dk][m], acc[t][m]);
        }
    }
    #pragma unroll
    for (int t = 0; t < 3; ++t) {
        u16x8 o;
        #pragma unroll
        for (int m = 0; m < 8; ++m) o[m] = f2bf(acc[t][m]);
        *(u16x8*)&out[(size_t)((i * SD + j) * SD + k0 + t) * 128 + c] = o;
    }
}

// ---------------------------------------------------------------------------
// shift-D + fc3 (swapped-operand MFMA: D col = n) + GELU + residual(t bf16)
// + LN(gn,bn) with shfl+2KB-LDS cross-wave stats + 64B-coalesced transposed store
__global__ __launch_bounds__(256) void k_final(
    const u16* __restrict__ in, const u16* __restrict__ wfrag, const float* __restrict__ bias,
    const u16* __restrict__ tin, const float* __restrict__ gn, const float* __restrict__ bn,
    float* __restrict__ out)
{
    __shared__ __align__(16) unsigned char smem[35840];
    u16* T = (u16*)(smem + 16384);          // [64 rows][136 u16] padded
    float* P1 = (float*)(smem + 33792);     // [4 wv][4 tb][16 n]
    float* P2 = (float*)(smem + 34816);
    const int tid = threadIdx.x;
    const int n0 = blockIdx.x * 64;

    // gather shifted h (D axis), u32 channel pairs -> swizzled A LDS
    for (int i = tid; i < 64 * 64; i += 256) {
        int row = i >> 6;
        int p = i & 63;
        int c = 2 * p;
        int n = n0 + row;
        int sh = c / 26 - 2;
        int coord = n % SD;
        int src = n - sh;
        int cs = coord - sh;
        unsigned v = 0;
        if (cs >= 0 && cs < SD) v = *(const unsigned*)&in[(size_t)src * 128 + c];
        *(unsigned*)(smem + row * 256 + ((4 * p) ^ ((row & 7) << 4))) = v;
    }
    // stage residual t tile (coalesced u16x8)
    for (int i = tid; i < 1024; i += 256) {
        int row = i >> 4;
        int c8 = (i & 15) * 8;
        *(u16x8*)&T[row * 136 + c8] = *(const u16x8*)&tin[(size_t)(n0 + row) * 128 + c8];
    }
    __syncthreads();

    const int lane = tid & 63;
    const int wv = tid >> 6;
    const int colb = lane & 15;
    const int q = lane >> 4;

    // wave wv owns channels 32wv..32wv+31 (co-tiles ta=0,1); all 4 n-tiles (tb)
    f32x4 acc[2][4];
    #pragma unroll
    for (int ta = 0; ta < 2; ++ta)
        #pragma unroll
        for (int tb = 0; tb < 4; ++tb)
            #pragma unroll
            for (int r4 = 0; r4 < 4; ++r4)
                acc[ta][tb][r4] = bias[wv * 32 + ta * 16 + q * 4 + r4];

    #pragma unroll
    for (int s = 0; s < 4; ++s) {
        s16x8 a[2];
        #pragma unroll
        for (int ta = 0; ta < 2; ++ta)
            a[ta] = *(const s16x8*)&wfrag[(((2 * wv + ta) * 4 + s) * 64 + lane) * 8];
        #pragma unroll
        for (int tb = 0; tb < 4; ++tb) {
            int row = tb * 16 + colb;
            s16x8 b = *(const s16x8*)(smem + row * 256 + ((s * 64 + q * 16) ^ ((row & 7) << 4)));
            #pragma unroll
            for (int ta = 0; ta < 2; ++ta)
                acc[ta][tb] = __builtin_amdgcn_mfma_f32_16x16x32_bf16(a[ta], b, acc[ta][tb], 0, 0, 0);
        }
    }

    // GELU + residual + per-(n) partial stats over this wave's 32 channels
    float v[2][4][4];
    float s1[4] = {0.f,0.f,0.f,0.f}, s2[4] = {0.f,0.f,0.f,0.f};
    #pragma unroll
    for (int tb = 0; tb < 4; ++tb) {
        int nn = tb * 16 + colb;
        #pragma unroll
        for (int ta = 0; ta < 2; ++ta)
            #pragma unroll
            for (int r4 = 0; r4 < 4; ++r4) {
                int co = wv * 32 + ta * 16 + q * 4 + r4;
                float hv = acc[ta][tb][r4];
                float ge = 0.5f * hv * (1.f + erff(hv * 0.70710678118654752f));
                float val = ge + bf2f(T[nn * 136 + co]);
                v[ta][tb][r4] = val;
                s1[tb] += val; s2[tb] += val * val;
            }
    }
    #pragma unroll
    for (int tb = 0; tb < 4; ++tb) {
        s1[tb] += __shfl_xor(s1[tb], 16);
        s2[tb] += __shfl_xor(s2[tb], 16);
        s1[tb] += __shfl_xor(s1[tb], 32);
        s2[tb] += __shfl_xor(s2[tb], 32);
    }
    if (lane < 16) {
        #pragma unroll
        for (int tb = 0; tb < 4; ++tb) {
            P1[(wv * 4 + tb) * 16 + lane] = s1[tb];
            P2[(wv * 4 + tb) * 16 + lane] = s2[tb];
        }
    }
    __syncthreads();

    float gnv[2][4], bnv[2][4];
    #pragma unroll
    for (int ta = 0; ta < 2; ++ta)
        #pragma unroll
        for (int r4 = 0; r4 < 4; ++r4) {
            int co = wv * 32 + ta * 16 + q * 4 + r4;
            gnv[ta][r4] = gn[co]; bnv[ta][r4] = bn[co];
        }
    #pragma unroll
    for (int tb = 0; tb < 4; ++tb) {
        float a = 0.f, bs = 0.f;
        #pragma unroll
        for (int w2 = 0; w2 < 4; ++w2) {
            a  += P1[(w2 * 4 + tb) * 16 + colb];
            bs += P2[(w2 * 4 + tb) * 16 + colb];
        }
        float mean = a * (1.f / 128.f);
        float var  = fmaxf(bs * (1.f / 128.f) - mean * mean, 0.f);
        float rstd = rsqrtf(var + 1e-5f);
        int nn = tb * 16 + colb;
        #pragma unroll
        for (int ta = 0; ta < 2; ++ta)
            #pragma unroll
            for (int r4 = 0; r4 < 4; ++r4) {
                int co = wv * 32 + ta * 16 + q * 4 + r4;
                float o = (v[ta][tb][r4] - mean) * rstd * gnv[ta][r4] + bnv[ta][r4];
                out[(size_t)co * NTOT + n0 + nn] = o;   // 16-lane 64B segments
            }
    }
}

// ---------------------------------------------------------------------------
extern "C" void kernel_launch(void* const* d_in, const int* in_sizes, int n_in,
                              void* d_out, int out_size, void* d_ws, size_t ws_size,
                              hipStream_t stream)
{
    const float* x    = (const float*)d_in[0];
    const float* pw   = (const float*)d_in[1];
    const float* pb   = (const float*)d_in[2];
    const float* g0   = (const float*)d_in[3];
    const float* b0   = (const float*)d_in[4];
    const float* g2   = (const float*)d_in[5];
    const float* b2   = (const float*)d_in[6];
    const float* fc1w = (const float*)d_in[7];
    const float* fc1b = (const float*)d_in[8];
    const float* dw1w = (const float*)d_in[9];
    const float* dw1b = (const float*)d_in[10];
    const float* fc2w = (const float*)d_in[11];
    const float* fc2b = (const float*)d_in[12];
    const float* dw2w = (const float*)d_in[13];
    const float* dw2b = (const float*)d_in[14];
    const float* fc3w = (const float*)d_in[15];
    const float* fc3b = (const float*)d_in[16];
    const float* gn   = (const float*)d_in[17];
    const float* bn   = (const float*)d_in[18];
    float* out = (float*)d_out;

    u16* tbuf = (u16*)d_ws;                      // NTOT*128 bf16
    u16* h1   = tbuf + (size_t)NTOT * 128;       // NTOT*128 bf16
    u16* h2   = h1 + (size_t)NTOT * 128;         // NTOT*128 bf16
    u16* wfP  = h2 + (size_t)NTOT * 128;         // 16384 u16 each
    u16* wf1  = wfP + 16384;
    u16* wf2  = wf1 + 16384;
    u16* wf3  = wf2 + 16384;
    float* dwT1 = (float*)(wf3 + 16384);         // 27*128 f32
    float* dwT2 = dwT1 + 27 * 128;

    k_mkfrag<<<8, 256, 0, stream>>>(pw, wfP, 108);
    k_mkfrag<<<8, 256, 0, stream>>>(fc1w, wf1, 128);
    k_mkfrag<<<8, 256, 0, stream>>>(fc2w, wf2, 128);
    k_mkfrag<<<8, 256, 0, stream>>>(fc3w, wf3, 128);
    k_transpose_w<<<14, 256, 0, stream>>>(dw1w, dwT1, 27);
    k_transpose_w<<<14, 256, 0, stream>>>(dw2w, dwT2, 27);

    k_proj_ln<<<NTOT / 64, 256, 0, stream>>>(x, wfP, pb, g0, b0, g2, b2, tbuf, h1);
    k_shift_mm<0><<<NTOT / 128, 256, 0, stream>>>(h1, wf1, fc1b, h2);
    k_dw<<<SWD, 256, 0, stream>>>(h2, dwT1, dw1b, h1);
    k_shift_mm<1><<<NTOT / 128, 256, 0, stream>>>(h1, wf2, fc2b, h2);
    k_dw<<<SWD, 256, 0, stream>>>(h2, dwT2, dw2b, h1);
    k_final<<<NTOT / 64, 256, 0, stream>>>(h1, wf3, fc3b, tbuf, gn, bn, out);
}

// Round 5
// 247.951 us; speedup vs baseline: 4.2540x; 1.0909x over previous
//
#include <hip/hip_runtime.h>
#include <hip/hip_bf16.h>
#include <math.h>

#define NTOT 110592   // 48^3
#define SD 48
#define SWD 2304      // 48*48

typedef short s16x8 __attribute__((ext_vector_type(8)));
typedef unsigned short u16x8 __attribute__((ext_vector_type(8)));
typedef float f32x4 __attribute__((ext_vector_type(4)));
typedef unsigned short u16;

__device__ __forceinline__ float bf2f(u16 u) {
    unsigned int x = ((unsigned int)u) << 16;
    float f; __builtin_memcpy(&f, &x, 4); return f;
}
__device__ __forceinline__ u16 f2bf(float f) {
    __hip_bfloat16 h = __float2bfloat16(f);
    u16 u; __builtin_memcpy(&u, &h, 2); return u;
}
__device__ __forceinline__ u16x8 zero8() {
    u16x8 z;
    #pragma unroll
    for (int j = 0; j < 8; ++j) z[j] = 0;
    return z;
}

// fast GELU (tanh form): max abs dev from exact ~1e-3, far under tolerance
__device__ __forceinline__ float gelu_f(float x) {
    float y = x * (0.7978845608f + 0.0356774081f * x * x);   // sqrt(2/pi)(x+0.044715x^3)
    float e = exp2f(y * 2.885390082f);                        // e^{2y}
    return x - x * __builtin_amdgcn_rcpf(e + 1.f);            // x*e/(e+1)
}

// load shifted h[n][cbase..cbase+7] (bf16), axial shift along stride STR.
// group g=c/26, shift s=g-2; value = (coord-s in [0,SD)) ? in[(n-s*STR)*128+c] : 0
__device__ __forceinline__ u16x8 ld_shift8(const u16* __restrict__ in, int n, int coord,
                                           int STR, int cbase) {
    int g = cbase / 26;
    int split = 26 * (g + 1) - cbase;     // elems belonging to group g (>=8: no straddle)
    int sh0 = g - 2;
    int cs0 = coord - sh0;
    u16x8 lo = zero8();
    if (cs0 >= 0 && cs0 < SD) lo = *(const u16x8*)&in[(size_t)(n - sh0 * STR) * 128 + cbase];
    if (split >= 8) return lo;
    u16x8 hi = zero8();
    int cs1 = cs0 - 1;
    if (cs1 >= 0 && cs1 < SD) hi = *(const u16x8*)&in[(size_t)(n - (sh0 + 1) * STR) * 128 + cbase];
    u16x8 r;
    #pragma unroll
    for (int j = 0; j < 8; ++j) r[j] = (j < split) ? lo[j] : hi[j];
    return r;
}

// ---------------------------------------------------------------------------
// transpose weights (f32): dst[k*128+co] = src[co*K + k]   (for depthwise w)
__global__ __launch_bounds__(256) void k_transpose_w(const float* __restrict__ src,
                                                     float* __restrict__ dst, int K) {
    int idx = blockIdx.x * 256 + threadIdx.x;
    if (idx >= K * 128) return;
    int k = idx >> 7;
    int co = idx & 127;
    dst[idx] = src[co * K + k];
}

// ---------------------------------------------------------------------------
// pack weights [128 co][K] into MFMA fragment layout (bf16), K padded to 128:
// dst[((t*4+s)*64 + lane)*8 + j] = w[16t+(lane&15)][32s + 8*(lane>>4) + j]
__global__ __launch_bounds__(256) void k_mkfrag(const float* __restrict__ src,
                                                u16* __restrict__ dst, int K) {
    int idx = blockIdx.x * 256 + threadIdx.x;   // [0, 2048)
    if (idx >= 2048) return;
    int lane = idx & 63;
    int s = (idx >> 6) & 3;
    int t = idx >> 8;
    int co = t * 16 + (lane & 15);
    int kb = s * 32 + (lane >> 4) * 8;
    #pragma unroll
    for (int j = 0; j < 8; ++j) {
        int k = kb + j;
        float v = (k < K) ? src[co * K + k] : 0.f;
        dst[idx * 8 + j] = f2bf(v);
    }
}

// ---------------------------------------------------------------------------
// proj conv (im2col MFMA, K=108 pad 128) + LN0 -> t(bf16), LN2 -> h(bf16)
__global__ __launch_bounds__(256) void k_proj_ln(
    const float* __restrict__ x, const u16* __restrict__ wfrag, const float* __restrict__ pb,
    const float* __restrict__ g0, const float* __restrict__ b0,
    const float* __restrict__ g2, const float* __restrict__ b2,
    u16* __restrict__ t_out, u16* __restrict__ h_out)
{
    __shared__ __align__(16) unsigned char smem[32768];   // A(16K) -> Tt(16K)+Th(16K)
    const int tid = threadIdx.x;
    const int n0 = blockIdx.x * 64;

    // im2col gather -> swizzled bf16 LDS [64 rows][128 k]
    for (int idx = tid; idx < 64 * 128; idx += 256) {
        int r = idx >> 7;
        int k = idx & 127;
        float v = 0.f;
        if (k < 108) {
            int ci = k / 27;  int mm = k - ci * 27;
            int ti = mm / 9;  int mj = mm - ti * 9;
            int tj = mj / 3;  int tk = mj - tj * 3;
            int n = n0 + r;
            int oi = n / SWD; int rem = n - oi * SWD;
            int oj = rem / SD; int ok = rem - oj * SD;
            int ii = 2 * oi + ti - 1;
            int ij = 2 * oj + tj - 1;
            int ik = 2 * ok + tk - 1;
            if (ii >= 0 && ii < 96 && ij >= 0 && ij < 96 && ik >= 0 && ik < 96)
                v = x[((ci * 96 + ii) * 96 + ij) * 96 + ik];
        }
        int byte = r * 256 + ((2 * k) ^ ((r & 7) << 4));
        *(u16*)(smem + byte) = f2bf(v);
    }
    __syncthreads();

    const int lane = tid & 63;
    const int wv = tid >> 6;
    const int rb = wv * 16;
    const int colb = lane & 15;
    const int q = lane >> 4;
    const int arow = rb + colb;
    const int aswz = (arow & 7) << 4;

    f32x4 acc[8];
    #pragma unroll
    for (int t = 0; t < 8; ++t) {
        float bb = pb[t * 16 + colb];
        acc[t][0] = bb; acc[t][1] = bb; acc[t][2] = bb; acc[t][3] = bb;
    }
    #pragma unroll
    for (int s = 0; s < 4; ++s) {
        s16x8 a = *(const s16x8*)(smem + arow * 256 + ((s * 64 + q * 16) ^ aswz));
        #pragma unroll
        for (int t = 0; t < 8; ++t) {
            s16x8 b = *(const s16x8*)&wfrag[((t * 4 + s) * 64 + lane) * 8];
            acc[t] = __builtin_amdgcn_mfma_f32_16x16x32_bf16(a, b, acc[t], 0, 0, 0);
        }
    }

    // LN0 stats in regs
    float s1[4] = {0.f,0.f,0.f,0.f}, s2[4] = {0.f,0.f,0.f,0.f};
    #pragma unroll
    for (int t = 0; t < 8; ++t)
        #pragma unroll
        for (int r4 = 0; r4 < 4; ++r4) {
            float v = acc[t][r4];
            s1[r4] += v; s2[r4] += v * v;
        }
    #pragma unroll
    for (int r4 = 0; r4 < 4; ++r4)
        #pragma unroll
        for (int m = 1; m < 16; m <<= 1) {
            s1[r4] += __shfl_xor(s1[r4], m);
            s2[r4] += __shfl_xor(s2[r4], m);
        }

    float g0v[8], b0v[8], g2v[8], b2v[8];
    #pragma unroll
    for (int t = 0; t < 8; ++t) {
        int c = t * 16 + colb;
        g0v[t] = g0[c]; b0v[t] = b0[c]; g2v[t] = g2[c]; b2v[t] = b2[c];
    }

    float tval[8][4];
    float u1[4] = {0.f,0.f,0.f,0.f}, u2[4] = {0.f,0.f,0.f,0.f};
    #pragma unroll
    for (int r4 = 0; r4 < 4; ++r4) {
        float mean = s1[r4] * (1.f / 128.f);
        float var  = fmaxf(s2[r4] * (1.f / 128.f) - mean * mean, 0.f);
        float rstd = rsqrtf(var + 1e-5f);
        #pragma unroll
        for (int t = 0; t < 8; ++t) {
            float tv = (acc[t][r4] - mean) * rstd * g0v[t] + b0v[t];
            tval[t][r4] = tv;
            u1[r4] += tv; u2[r4] += tv * tv;
        }
    }
    #pragma unroll
    for (int r4 = 0; r4 < 4; ++r4)
        #pragma unroll
        for (int m = 1; m < 16; m <<= 1) {
            u1[r4] += __shfl_xor(u1[r4], m);
            u2[r4] += __shfl_xor(u2[r4], m);
        }
    __syncthreads();   // A dead; reuse LDS for t/h dumps

    #pragma unroll
    for (int r4 = 0; r4 < 4; ++r4) {
        float mean2 = u1[r4] * (1.f / 128.f);
        float var2  = fmaxf(u2[r4] * (1.f / 128.f) - mean2 * mean2, 0.f);
        float rstd2 = rsqrtf(var2 + 1e-5f);
        int row = rb + q * 4 + r4;
        int rsw = (row & 7) << 4;
        #pragma unroll
        for (int t = 0; t < 8; ++t) {
            int col = t * 16 + colb;
            float tv = tval[t][r4];
            float hv = (tv - mean2) * rstd2 * g2v[t] + b2v[t];
            int off = (2 * col) ^ rsw;
            *(u16*)(smem + row * 256 + off)         = f2bf(tv);
            *(u16*)(smem + 16384 + row * 256 + off) = f2bf(hv);
        }
    }
    __syncthreads();
    for (int i = tid; i < 1024; i += 256) {
        int row = i >> 4;
        int c8 = (i & 15) * 8;
        int byte = row * 256 + ((2 * c8) ^ ((row & 7) << 4));
        *(u16x8*)&t_out[(size_t)(n0 + row) * 128 + c8] = *(const u16x8*)(smem + byte);
        *(u16x8*)&h_out[(size_t)(n0 + row) * 128 + c8] = *(const u16x8*)(smem + 16384 + byte);
    }
}

// ---------------------------------------------------------------------------
// axial shift + matmul, no A-LDS: activation fragments loaded directly from
// global with shift applied in the address. 64 rows/block, 4 waves.
template <int AXIS>
__global__ __launch_bounds__(256) void k_shift_mm(
    const u16* __restrict__ in, const u16* __restrict__ wfrag, const float* __restrict__ bias,
    u16* __restrict__ out)
{
    __shared__ u16 O[64 * 136];   // 17.4 KB output staging
    const int tid = threadIdx.x;
    const int n0 = blockIdx.x * 64;
    const int lane = tid & 63;
    const int wv = tid >> 6;
    const int colb = lane & 15;
    const int q = lane >> 4;

    const int arow = wv * 16 + colb;
    const int n = n0 + arow;
    const int STR = (AXIS == 0) ? SWD : (AXIS == 1) ? SD : 1;
    const int coord = (AXIS == 0) ? n / SWD : (AXIS == 1) ? (n / SD) % SD : n % SD;

    f32x4 acc[8];
    #pragma unroll
    for (int t = 0; t < 8; ++t) {
        float bb = bias[t * 16 + colb];
        acc[t][0] = bb; acc[t][1] = bb; acc[t][2] = bb; acc[t][3] = bb;
    }
    #pragma unroll
    for (int s = 0; s < 4; ++s) {
        u16x8 av = ld_shift8(in, n, coord, STR, s * 32 + q * 8);
        s16x8 a = *(s16x8*)&av;
        #pragma unroll
        for (int t = 0; t < 8; ++t) {
            s16x8 b = *(const s16x8*)&wfrag[((t * 4 + s) * 64 + lane) * 8];
            acc[t] = __builtin_amdgcn_mfma_f32_16x16x32_bf16(a, b, acc[t], 0, 0, 0);
        }
    }
    // stage D (row = n-within-tile = q*4+r4, col = co = t*16+colb) into LDS
    #pragma unroll
    for (int r4 = 0; r4 < 4; ++r4) {
        int row = wv * 16 + q * 4 + r4;
        #pragma unroll
        for (int t = 0; t < 8; ++t)
            O[row * 136 + t * 16 + colb] = f2bf(acc[t][r4]);
    }
    __syncthreads();
    for (int i = tid; i < 1024; i += 256) {
        int row = i >> 4;
        int c8 = (i & 15) * 8;
        *(u16x8*)&out[(size_t)(n0 + row) * 128 + c8] = *(const u16x8*)&O[row * 136 + c8];
    }
}

// ---------------------------------------------------------------------------
// depthwise 3x3x3 conv, bf16 io; wt f32 [27 taps][128 c]; thread: 8 ch x 3 k
__global__ __launch_bounds__(256) void k_dw(
    const u16* __restrict__ in, const float* __restrict__ wt, const float* __restrict__ b,
    u16* __restrict__ out)
{
    const int tid = threadIdx.x;
    const int cg = tid & 15;       // c = cg*8
    const int kq = tid >> 4;       // 0..15 -> k0 = kq*3
    const int k0 = kq * 3;
    const int ij = blockIdx.x;
    const int i = ij / SD;
    const int j = ij - i * SD;
    const int c = cg * 8;

    float acc[3][8];
    {
        float4 ba = *(const float4*)&b[c];
        float4 bb = *(const float4*)&b[c + 4];
        #pragma unroll
        for (int t = 0; t < 3; ++t) {
            acc[t][0] = ba.x; acc[t][1] = ba.y; acc[t][2] = ba.z; acc[t][3] = ba.w;
            acc[t][4] = bb.x; acc[t][5] = bb.y; acc[t][6] = bb.z; acc[t][7] = bb.w;
        }
    }

    #pragma unroll
    for (int di = -1; di <= 1; ++di) {
        int ii = i + di;
        if (ii < 0 || ii >= SD) continue;
        #pragma unroll
        for (int dj = -1; dj <= 1; ++dj) {
            int jj = j + dj;
            if (jj < 0 || jj >= SD) continue;
            const u16* base = &in[(size_t)((ii * SD + jj) * SD) * 128 + c];
            const int tap0 = ((di + 1) * 3 + (dj + 1)) * 3;
            float wv[3][8];
            #pragma unroll
            for (int dk = 0; dk < 3; ++dk) {
                float4 wa = *(const float4*)&wt[(tap0 + dk) * 128 + c];
                float4 wb = *(const float4*)&wt[(tap0 + dk) * 128 + c + 4];
                wv[dk][0] = wa.x; wv[dk][1] = wa.y; wv[dk][2] = wa.z; wv[dk][3] = wa.w;
                wv[dk][4] = wb.x; wv[dk][5] = wb.y; wv[dk][6] = wb.z; wv[dk][7] = wb.w;
            }
            float v[5][8];
            #pragma unroll
            for (int s = 0; s < 5; ++s) {
                int kk = k0 + s - 1;
                if (kk >= 0 && kk < SD) {
                    u16x8 u = *(const u16x8*)(base + (size_t)kk * 128);
                    #pragma unroll
                    for (int m = 0; m < 8; ++m) v[s][m] = bf2f(u[m]);
                } else {
                    #pragma unroll
                    for (int m = 0; m < 8; ++m) v[s][m] = 0.f;
                }
            }
            #pragma unroll
            for (int t = 0; t < 3; ++t)
                #pragma unroll
                for (int dk = 0; dk < 3; ++dk)
                    #pragma unroll
                    for (int m = 0; m < 8; ++m)
                        acc[t][m] = fmaf(wv[dk][m], v[t + dk][m], acc[t][m]);
        }
    }
    #pragma unroll
    for (int t = 0; t < 3; ++t) {
        u16x8 o;
        #pragma unroll
        for (int m = 0; m < 8; ++m) o[m] = f2bf(acc[t][m]);
        *(u16x8*)&out[(size_t)((i * SD + j) * SD + k0 + t) * 128 + c] = o;
    }
}

// ---------------------------------------------------------------------------
// shift-D + fc3 (swapped MFMA, direct global B-frags) + fast GELU + residual
// + wave-local LN + transposed store. Wave = one 16-row n-tile; LDS = T only.
__global__ __launch_bounds__(256) void k_final(
    const u16* __restrict__ in, const u16* __restrict__ wfrag, const float* __restrict__ bias,
    const u16* __restrict__ tin, const float* __restrict__ gn, const float* __restrict__ bn,
    float* __restrict__ out)
{
    __shared__ u16 T[64 * 136];   // residual tile, 17.4 KB
    const int tid = threadIdx.x;
    const int n0 = blockIdx.x * 64;
    const int lane = tid & 63;
    const int wv = tid >> 6;       // = n-tile (tb)
    const int colb = lane & 15;
    const int q = lane >> 4;

    // stage residual t tile (coalesced u16x8)
    for (int i = tid; i < 1024; i += 256) {
        int row = i >> 4;
        int c8 = (i & 15) * 8;
        *(u16x8*)&T[row * 136 + c8] = *(const u16x8*)&tin[(size_t)(n0 + row) * 128 + c8];
    }

    const int nn = wv * 16 + colb;    // this lane's output row (D col)
    const int n = n0 + nn;
    const int coord = n % SD;

    // acc[ta]: D rows = co = ta*16 + q*4 + r4, D col = nn
    f32x4 acc[8];
    #pragma unroll
    for (int ta = 0; ta < 8; ++ta)
        #pragma unroll
        for (int r4 = 0; r4 < 4; ++r4)
            acc[ta][r4] = bias[ta * 16 + q * 4 + r4];

    #pragma unroll
    for (int s = 0; s < 4; ++s) {
        u16x8 bv = ld_shift8(in, n, coord, 1, s * 32 + q * 8);
        s16x8 b = *(s16x8*)&bv;
        #pragma unroll
        for (int ta = 0; ta < 8; ++ta) {
            s16x8 a = *(const s16x8*)&wfrag[((ta * 4 + s) * 64 + lane) * 8];
            acc[ta] = __builtin_amdgcn_mfma_f32_16x16x32_bf16(a, b, acc[ta], 0, 0, 0);
        }
    }
    __syncthreads();   // T ready

    // GELU + residual + full-128 LN stats (wave-local: butterfly over q)
    float val[8][4];
    float s1 = 0.f, s2 = 0.f;
    #pragma unroll
    for (int ta = 0; ta < 8; ++ta)
        #pragma unroll
        for (int r4 = 0; r4 < 4; ++r4) {
            int co = ta * 16 + q * 4 + r4;
            float v = gelu_f(acc[ta][r4]) + bf2f(T[nn * 136 + co]);
            val[ta][r4] = v;
            s1 += v; s2 += v * v;
        }
    s1 += __shfl_xor(s1, 16); s2 += __shfl_xor(s2, 16);
    s1 += __shfl_xor(s1, 32); s2 += __shfl_xor(s2, 32);
    float mean = s1 * (1.f / 128.f);
    float var  = fmaxf(s2 * (1.f / 128.f) - mean * mean, 0.f);
    float rstd = rsqrtf(var + 1e-5f);

    #pragma unroll
    for (int ta = 0; ta < 8; ++ta)
        #pragma unroll
        for (int r4 = 0; r4 < 4; ++r4) {
            int co = ta * 16 + q * 4 + r4;
            float o = (val[ta][r4] - mean) * rstd * gn[co] + bn[co];
            out[(size_t)co * NTOT + n] = o;
        }
}

// ---------------------------------------------------------------------------
extern "C" void kernel_launch(void* const* d_in, const int* in_sizes, int n_in,
                              void* d_out, int out_size, void* d_ws, size_t ws_size,
                              hipStream_t stream)
{
    const float* x    = (const float*)d_in[0];
    const float* pw   = (const float*)d_in[1];
    const float* pb   = (const float*)d_in[2];
    const float* g0   = (const float*)d_in[3];
    const float* b0   = (const float*)d_in[4];
    const float* g2   = (const float*)d_in[5];
    const float* b2   = (const float*)d_in[6];
    const float* fc1w = (const float*)d_in[7];
    const float* fc1b = (const float*)d_in[8];
    const float* dw1w = (const float*)d_in[9];
    const float* dw1b = (const float*)d_in[10];
    const float* fc2w = (const float*)d_in[11];
    const float* fc2b = (const float*)d_in[12];
    const float* dw2w = (const float*)d_in[13];
    const float* dw2b = (const float*)d_in[14];
    const float* fc3w = (const float*)d_in[15];
    const float* fc3b = (const float*)d_in[16];
    const float* gn   = (const float*)d_in[17];
    const float* bn   = (const float*)d_in[18];
    float* out = (float*)d_out;

    u16* tbuf = (u16*)d_ws;                      // NTOT*128 bf16
    u16* h1   = tbuf + (size_t)NTOT * 128;       // NTOT*128 bf16
    u16* h2   = h1 + (size_t)NTOT * 128;         // NTOT*128 bf16
    u16* wfP  = h2 + (size_t)NTOT * 128;         // 16384 u16 each
    u16* wf1  = wfP + 16384;
    u16* wf2  = wf1 + 16384;
    u16* wf3  = wf2 + 16384;
    float* dwT1 = (float*)(wf3 + 16384);         // 27*128 f32
    float* dwT2 = dwT1 + 27 * 128;

    k_mkfrag<<<8, 256, 0, stream>>>(pw, wfP, 108);
    k_mkfrag<<<8, 256, 0, stream>>>(fc1w, wf1, 128);
    k_mkfrag<<<8, 256, 0, stream>>>(fc2w, wf2, 128);
    k_mkfrag<<<8, 256, 0, stream>>>(fc3w, wf3, 128);
    k_transpose_w<<<14, 256, 0, stream>>>(dw1w, dwT1, 27);
    k_transpose_w<<<14, 256, 0, stream>>>(dw2w, dwT2, 27);

    k_proj_ln<<<NTOT / 64, 256, 0, stream>>>(x, wfP, pb, g0, b0, g2, b2, tbuf, h1);
    k_shift_mm<0><<<NTOT / 64, 256, 0, stream>>>(h1, wf1, fc1b, h2);
    k_dw<<<SWD, 256, 0, stream>>>(h2, dwT1, dw1b, h1);
    k_shift_mm<1><<<NTOT / 64, 256, 0, stream>>>(h1, wf2, fc2b, h2);
    k_dw<<<SWD, 256, 0, stream>>>(h2, dwT2, dw2b, h1);
    k_final<<<NTOT / 64, 256, 0, stream>>>(h1, wf3, fc3b, tbuf, gn, bn, out);
}

// Round 6
// 222.455 us; speedup vs baseline: 4.7416x; 1.1146x over previous
//
#include <hip/hip_runtime.h>
#include <hip/hip_bf16.h>
#include <math.h>

#define NTOT 110592   // 48^3
#define SD 48
#define SWD 2304      // 48*48

typedef short s16x8 __attribute__((ext_vector_type(8)));
typedef unsigned short u16x8 __attribute__((ext_vector_type(8)));
typedef float f32x4 __attribute__((ext_vector_type(4)));
typedef unsigned short u16;

__device__ __forceinline__ float bf2f(u16 u) {
    unsigned int x = ((unsigned int)u) << 16;
    float f; __builtin_memcpy(&f, &x, 4); return f;
}
__device__ __forceinline__ u16 f2bf(float f) {
    __hip_bfloat16 h = __float2bfloat16(f);
    u16 u; __builtin_memcpy(&u, &h, 2); return u;
}
__device__ __forceinline__ u16x8 zero8() {
    u16x8 z;
    #pragma unroll
    for (int j = 0; j < 8; ++j) z[j] = 0;
    return z;
}

// fast GELU (tanh form): max abs dev from exact ~1e-3, far under tolerance
__device__ __forceinline__ float gelu_f(float x) {
    float y = x * (0.7978845608f + 0.0356774081f * x * x);   // sqrt(2/pi)(x+0.044715x^3)
    float e = exp2f(y * 2.885390082f);                        // e^{2y}
    return x - x * __builtin_amdgcn_rcpf(e + 1.f);            // x*e/(e+1)
}

// load shifted h[n][cbase..cbase+7] (bf16), axial shift along stride STR.
__device__ __forceinline__ u16x8 ld_shift8(const u16* __restrict__ in, int n, int coord,
                                           int STR, int cbase) {
    int g = cbase / 26;
    int split = 26 * (g + 1) - cbase;     // elems belonging to group g (>=8: no straddle)
    int sh0 = g - 2;
    int cs0 = coord - sh0;
    u16x8 lo = zero8();
    if (cs0 >= 0 && cs0 < SD) lo = *(const u16x8*)&in[(size_t)(n - sh0 * STR) * 128 + cbase];
    if (split >= 8) return lo;
    u16x8 hi = zero8();
    int cs1 = cs0 - 1;
    if (cs1 >= 0 && cs1 < SD) hi = *(const u16x8*)&in[(size_t)(n - (sh0 + 1) * STR) * 128 + cbase];
    u16x8 r;
    #pragma unroll
    for (int j = 0; j < 8; ++j) r[j] = (j < split) ? lo[j] : hi[j];
    return r;
}

// ---------------------------------------------------------------------------
// merged prep: blocks 0-31 pack the 4 fc/proj weights into MFMA fragments;
// blocks 32-59 transpose the 2 depthwise weights to [tap][c]
__global__ __launch_bounds__(256) void k_prep(
    const float* __restrict__ pw, const float* __restrict__ fc1w,
    const float* __restrict__ fc2w, const float* __restrict__ fc3w,
    const float* __restrict__ dw1w, const float* __restrict__ dw2w,
    u16* __restrict__ wfP, u16* __restrict__ wf1, u16* __restrict__ wf2,
    u16* __restrict__ wf3, float* __restrict__ dwT1, float* __restrict__ dwT2)
{
    int b = blockIdx.x;
    if (b < 32) {
        int which = b >> 3;
        const float* src = (which == 0) ? pw : (which == 1) ? fc1w : (which == 2) ? fc2w : fc3w;
        u16* dst = (which == 0) ? wfP : (which == 1) ? wf1 : (which == 2) ? wf2 : wf3;
        int K = (which == 0) ? 108 : 128;
        int idx = (b & 7) * 256 + threadIdx.x;
        int lane = idx & 63;
        int s = (idx >> 6) & 3;
        int t = idx >> 8;
        int co = t * 16 + (lane & 15);
        int kb = s * 32 + (lane >> 4) * 8;
        #pragma unroll
        for (int j = 0; j < 8; ++j) {
            int k = kb + j;
            float v = (k < K) ? src[co * K + k] : 0.f;
            dst[idx * 8 + j] = f2bf(v);
        }
    } else {
        int which = (b - 32) / 14;
        int bb = (b - 32) % 14;
        const float* src = which ? dw2w : dw1w;
        float* dst = which ? dwT2 : dwT1;
        int idx = bb * 256 + threadIdx.x;
        if (idx < 27 * 128) {
            int k = idx >> 7;
            int co = idx & 127;
            dst[idx] = src[co * 27 + k];
        }
    }
}

// ---------------------------------------------------------------------------
// proj conv (im2col MFMA, K=108 pad 128) + LN0 -> t(bf16), LN2 -> h(bf16)
// staging: wave = ci, lane = row; static 3x3x3 tap loop, minimal bounds.
__global__ __launch_bounds__(256) void k_proj_ln(
    const float* __restrict__ x, const u16* __restrict__ wfrag, const float* __restrict__ pb,
    const float* __restrict__ g0, const float* __restrict__ b0,
    const float* __restrict__ g2, const float* __restrict__ b2,
    u16* __restrict__ t_out, u16* __restrict__ h_out)
{
    __shared__ __align__(16) unsigned char smem[32768];   // A(16K) -> Tt(16K)+Th(16K)
    const int tid = threadIdx.x;
    const int n0 = blockIdx.x * 64;

    // im2col gather -> swizzled bf16 LDS [64 rows][128 k]
    {
        const int ci = tid >> 6;    // wave index = input channel
        const int r  = tid & 63;    // row within tile
        const int rsw = (r & 7) << 4;
        unsigned char* dstrow = smem + r * 256;
        int n = n0 + r;
        int oi = n / SWD; int rem = n - oi * SWD;
        int oj = rem / SD; int ok = rem - oj * SD;
        const float* xb = x + (size_t)ci * (96 * 96 * 96);
        const int ik0 = 2 * ok - 1;
        #pragma unroll
        for (int ti = 0; ti < 3; ++ti) {
            int ii = 2 * oi + ti - 1;                 // <= 95 always
            bool iok = (ti > 0) || (ii >= 0);
            #pragma unroll
            for (int tj = 0; tj < 3; ++tj) {
                int ij = 2 * oj + tj - 1;             // <= 95 always
                bool jok = (tj > 0) || (ij >= 0);
                const float* row = xb + ((size_t)ii * 96 + ij) * 96;
                const int kbase = ci * 27 + ti * 9 + tj * 3;
                #pragma unroll
                for (int tk = 0; tk < 3; ++tk) {
                    int ik = ik0 + tk;                // <= 95 always
                    bool kok = (tk > 0) || (ik >= 0);
                    float v = (iok && jok && kok) ? row[ik] : 0.f;
                    int k = kbase + tk;
                    *(u16*)(dstrow + ((2 * k) ^ rsw)) = f2bf(v);
                }
            }
        }
        // zero-pad k = 108..127 (each ci writes 5)
        #pragma unroll
        for (int p = 0; p < 5; ++p) {
            int k = 108 + ci * 5 + p;
            *(u16*)(dstrow + ((2 * k) ^ rsw)) = 0;
        }
    }
    __syncthreads();

    const int lane = tid & 63;
    const int wv = tid >> 6;
    const int rb = wv * 16;
    const int colb = lane & 15;
    const int q = lane >> 4;
    const int arow = rb + colb;
    const int aswz = (arow & 7) << 4;

    f32x4 acc[8];
    #pragma unroll
    for (int t = 0; t < 8; ++t) {
        float bb = pb[t * 16 + colb];
        acc[t][0] = bb; acc[t][1] = bb; acc[t][2] = bb; acc[t][3] = bb;
    }
    #pragma unroll
    for (int s = 0; s < 4; ++s) {
        s16x8 a = *(const s16x8*)(smem + arow * 256 + ((s * 64 + q * 16) ^ aswz));
        #pragma unroll
        for (int t = 0; t < 8; ++t) {
            s16x8 b = *(const s16x8*)&wfrag[((t * 4 + s) * 64 + lane) * 8];
            acc[t] = __builtin_amdgcn_mfma_f32_16x16x32_bf16(a, b, acc[t], 0, 0, 0);
        }
    }

    // LN0 stats in regs
    float s1[4] = {0.f,0.f,0.f,0.f}, s2[4] = {0.f,0.f,0.f,0.f};
    #pragma unroll
    for (int t = 0; t < 8; ++t)
        #pragma unroll
        for (int r4 = 0; r4 < 4; ++r4) {
            float v = acc[t][r4];
            s1[r4] += v; s2[r4] += v * v;
        }
    #pragma unroll
    for (int r4 = 0; r4 < 4; ++r4)
        #pragma unroll
        for (int m = 1; m < 16; m <<= 1) {
            s1[r4] += __shfl_xor(s1[r4], m);
            s2[r4] += __shfl_xor(s2[r4], m);
        }

    float g0v[8], b0v[8], g2v[8], b2v[8];
    #pragma unroll
    for (int t = 0; t < 8; ++t) {
        int c = t * 16 + colb;
        g0v[t] = g0[c]; b0v[t] = b0[c]; g2v[t] = g2[c]; b2v[t] = b2[c];
    }

    float tval[8][4];
    float u1[4] = {0.f,0.f,0.f,0.f}, u2[4] = {0.f,0.f,0.f,0.f};
    #pragma unroll
    for (int r4 = 0; r4 < 4; ++r4) {
        float mean = s1[r4] * (1.f / 128.f);
        float var  = fmaxf(s2[r4] * (1.f / 128.f) - mean * mean, 0.f);
        float rstd = rsqrtf(var + 1e-5f);
        #pragma unroll
        for (int t = 0; t < 8; ++t) {
            float tv = (acc[t][r4] - mean) * rstd * g0v[t] + b0v[t];
            tval[t][r4] = tv;
            u1[r4] += tv; u2[r4] += tv * tv;
        }
    }
    #pragma unroll
    for (int r4 = 0; r4 < 4; ++r4)
        #pragma unroll
        for (int m = 1; m < 16; m <<= 1) {
            u1[r4] += __shfl_xor(u1[r4], m);
            u2[r4] += __shfl_xor(u2[r4], m);
        }
    __syncthreads();   // A dead; reuse LDS for t/h dumps

    #pragma unroll
    for (int r4 = 0; r4 < 4; ++r4) {
        float mean2 = u1[r4] * (1.f / 128.f);
        float var2  = fmaxf(u2[r4] * (1.f / 128.f) - mean2 * mean2, 0.f);
        float rstd2 = rsqrtf(var2 + 1e-5f);
        int row = rb + q * 4 + r4;
        int rsw = (row & 7) << 4;
        #pragma unroll
        for (int t = 0; t < 8; ++t) {
            int col = t * 16 + colb;
            float tv = tval[t][r4];
            float hv = (tv - mean2) * rstd2 * g2v[t] + b2v[t];
            int off = (2 * col) ^ rsw;
            *(u16*)(smem + row * 256 + off)         = f2bf(tv);
            *(u16*)(smem + 16384 + row * 256 + off) = f2bf(hv);
        }
    }
    __syncthreads();
    for (int i = tid; i < 1024; i += 256) {
        int row = i >> 4;
        int c8 = (i & 15) * 8;
        int byte = row * 256 + ((2 * c8) ^ ((row & 7) << 4));
        *(u16x8*)&t_out[(size_t)(n0 + row) * 128 + c8] = *(const u16x8*)(smem + byte);
        *(u16x8*)&h_out[(size_t)(n0 + row) * 128 + c8] = *(const u16x8*)(smem + 16384 + byte);
    }
}

// ---------------------------------------------------------------------------
// axial shift + matmul, no A-LDS: activation fragments loaded directly from
// global with shift applied in the address. 64 rows/block, 4 waves.
template <int AXIS>
__global__ __launch_bounds__(256) void k_shift_mm(
    const u16* __restrict__ in, const u16* __restrict__ wfrag, const float* __restrict__ bias,
    u16* __restrict__ out)
{
    __shared__ u16 O[64 * 136];   // 17.4 KB output staging
    const int tid = threadIdx.x;
    const int n0 = blockIdx.x * 64;
    const int lane = tid & 63;
    const int wv = tid >> 6;
    const int colb = lane & 15;
    const int q = lane >> 4;

    const int arow = wv * 16 + colb;
    const int n = n0 + arow;
    const int STR = (AXIS == 0) ? SWD : (AXIS == 1) ? SD : 1;
    const int coord = (AXIS == 0) ? n / SWD : (AXIS == 1) ? (n / SD) % SD : n % SD;

    f32x4 acc[8];
    #pragma unroll
    for (int t = 0; t < 8; ++t) {
        float bb = bias[t * 16 + colb];
        acc[t][0] = bb; acc[t][1] = bb; acc[t][2] = bb; acc[t][3] = bb;
    }
    #pragma unroll
    for (int s = 0; s < 4; ++s) {
        u16x8 av = ld_shift8(in, n, coord, STR, s * 32 + q * 8);
        s16x8 a = *(s16x8*)&av;
        #pragma unroll
        for (int t = 0; t < 8; ++t) {
            s16x8 b = *(const s16x8*)&wfrag[((t * 4 + s) * 64 + lane) * 8];
            acc[t] = __builtin_amdgcn_mfma_f32_16x16x32_bf16(a, b, acc[t], 0, 0, 0);
        }
    }
    // stage D (row = n-within-tile = q*4+r4, col = co = t*16+colb) into LDS
    #pragma unroll
    for (int r4 = 0; r4 < 4; ++r4) {
        int row = wv * 16 + q * 4 + r4;
        #pragma unroll
        for (int t = 0; t < 8; ++t)
            O[row * 136 + t * 16 + colb] = f2bf(acc[t][r4]);
    }
    __syncthreads();
    for (int i = tid; i < 1024; i += 256) {
        int row = i >> 4;
        int c8 = (i & 15) * 8;
        *(u16x8*)&out[(size_t)(n0 + row) * 128 + c8] = *(const u16x8*)&O[row * 136 + c8];
    }
}

// ---------------------------------------------------------------------------
// depthwise 3x3x3 conv, bf16 io; wt f32 [27 taps][128 c]; thread: 8 ch x 3 k
__global__ __launch_bounds__(256) void k_dw(
    const u16* __restrict__ in, const float* __restrict__ wt, const float* __restrict__ b,
    u16* __restrict__ out)
{
    const int tid = threadIdx.x;
    const int cg = tid & 15;       // c = cg*8
    const int kq = tid >> 4;       // 0..15 -> k0 = kq*3
    const int k0 = kq * 3;
    const int ij = blockIdx.x;
    const int i = ij / SD;
    const int j = ij - i * SD;
    const int c = cg * 8;

    float acc[3][8];
    {
        float4 ba = *(const float4*)&b[c];
        float4 bb = *(const float4*)&b[c + 4];
        #pragma unroll
        for (int t = 0; t < 3; ++t) {
            acc[t][0] = ba.x; acc[t][1] = ba.y; acc[t][2] = ba.z; acc[t][3] = ba.w;
            acc[t][4] = bb.x; acc[t][5] = bb.y; acc[t][6] = bb.z; acc[t][7] = bb.w;
        }
    }

    #pragma unroll
    for (int di = -1; di <= 1; ++di) {
        int ii = i + di;
        if (ii < 0 || ii >= SD) continue;
        #pragma unroll
        for (int dj = -1; dj <= 1; ++dj) {
            int jj = j + dj;
            if (jj < 0 || jj >= SD) continue;
            const u16* base = &in[(size_t)((ii * SD + jj) * SD) * 128 + c];
            const int tap0 = ((di + 1) * 3 + (dj + 1)) * 3;
            float wv[3][8];
            #pragma unroll
            for (int dk = 0; dk < 3; ++dk) {
                float4 wa = *(const float4*)&wt[(tap0 + dk) * 128 + c];
                float4 wb = *(const float4*)&wt[(tap0 + dk) * 128 + c + 4];
                wv[dk][0] = wa.x; wv[dk][1] = wa.y; wv[dk][2] = wa.z; wv[dk][3] = wa.w;
                wv[dk][4] = wb.x; wv[dk][5] = wb.y; wv[dk][6] = wb.z; wv[dk][7] = wb.w;
            }
            float v[5][8];
            #pragma unroll
            for (int s = 0; s < 5; ++s) {
                int kk = k0 + s - 1;
                if (kk >= 0 && kk < SD) {
                    u16x8 u = *(const u16x8*)(base + (size_t)kk * 128);
                    #pragma unroll
                    for (int m = 0; m < 8; ++m) v[s][m] = bf2f(u[m]);
                } else {
                    #pragma unroll
                    for (int m = 0; m < 8; ++m) v[s][m] = 0.f;
                }
            }
            #pragma unroll
            for (int t = 0; t < 3; ++t)
                #pragma unroll
                for (int dk = 0; dk < 3; ++dk)
                    #pragma unroll
                    for (int m = 0; m < 8; ++m)
                        acc[t][m] = fmaf(wv[dk][m], v[t + dk][m], acc[t][m]);
        }
    }
    #pragma unroll
    for (int t = 0; t < 3; ++t) {
        u16x8 o;
        #pragma unroll
        for (int m = 0; m < 8; ++m) o[m] = f2bf(acc[t][m]);
        *(u16x8*)&out[(size_t)((i * SD + j) * SD + k0 + t) * 128 + c] = o;
    }
}

// ---------------------------------------------------------------------------
// shift-D + fc3 (swapped MFMA, direct global B-frags) + fast GELU + residual
// + wave-local LN + transposed store. Wave = one 16-row n-tile; LDS = T only.
__global__ __launch_bounds__(256) void k_final(
    const u16* __restrict__ in, const u16* __restrict__ wfrag, const float* __restrict__ bias,
    const u16* __restrict__ tin, const float* __restrict__ gn, const float* __restrict__ bn,
    float* __restrict__ out)
{
    __shared__ u16 T[64 * 136];   // residual tile, 17.4 KB
    const int tid = threadIdx.x;
    const int n0 = blockIdx.x * 64;
    const int lane = tid & 63;
    const int wv = tid >> 6;       // = n-tile (tb)
    const int colb = lane & 15;
    const int q = lane >> 4;

    // stage residual t tile (coalesced u16x8)
    for (int i = tid; i < 1024; i += 256) {
        int row = i >> 4;
        int c8 = (i & 15) * 8;
        *(u16x8*)&T[row * 136 + c8] = *(const u16x8*)&tin[(size_t)(n0 + row) * 128 + c8];
    }

    const int nn = wv * 16 + colb;    // this lane's output row (D col)
    const int n = n0 + nn;
    const int coord = n % SD;

    // acc[ta]: D rows = co = ta*16 + q*4 + r4, D col = nn
    f32x4 acc[8];
    #pragma unroll
    for (int ta = 0; ta < 8; ++ta)
        #pragma unroll
        for (int r4 = 0; r4 < 4; ++r4)
            acc[ta][r4] = bias[ta * 16 + q * 4 + r4];

    #pragma unroll
    for (int s = 0; s < 4; ++s) {
        u16x8 bv = ld_shift8(in, n, coord, 1, s * 32 + q * 8);
        s16x8 b = *(s16x8*)&bv;
        #pragma unroll
        for (int ta = 0; ta < 8; ++ta) {
            s16x8 a = *(const s16x8*)&wfrag[((ta * 4 + s) * 64 + lane) * 8];
            acc[ta] = __builtin_amdgcn_mfma_f32_16x16x32_bf16(a, b, acc[ta], 0, 0, 0);
        }
    }
    __syncthreads();   // T ready

    // GELU + residual + full-128 LN stats (wave-local: butterfly over q)
    float val[8][4];
    float s1 = 0.f, s2 = 0.f;
    #pragma unroll
    for (int ta = 0; ta < 8; ++ta)
        #pragma unroll
        for (int r4 = 0; r4 < 4; ++r4) {
            int co = ta * 16 + q * 4 + r4;
            float v = gelu_f(acc[ta][r4]) + bf2f(T[nn * 136 + co]);
            val[ta][r4] = v;
            s1 += v; s2 += v * v;
        }
    s1 += __shfl_xor(s1, 16); s2 += __shfl_xor(s2, 16);
    s1 += __shfl_xor(s1, 32); s2 += __shfl_xor(s2, 32);
    float mean = s1 * (1.f / 128.f);
    float var  = fmaxf(s2 * (1.f / 128.f) - mean * mean, 0.f);
    float rstd = rsqrtf(var + 1e-5f);

    #pragma unroll
    for (int ta = 0; ta < 8; ++ta)
        #pragma unroll
        for (int r4 = 0; r4 < 4; ++r4) {
            int co = ta * 16 + q * 4 + r4;
            float o = (val[ta][r4] - mean) * rstd * gn[co] + bn[co];
            out[(size_t)co * NTOT + n] = o;
        }
}

// ---------------------------------------------------------------------------
extern "C" void kernel_launch(void* const* d_in, const int* in_sizes, int n_in,
                              void* d_out, int out_size, void* d_ws, size_t ws_size,
                              hipStream_t stream)
{
    const float* x    = (const float*)d_in[0];
    const float* pw   = (const float*)d_in[1];
    const float* pb   = (const float*)d_in[2];
    const float* g0   = (const float*)d_in[3];
    const float* b0   = (const float*)d_in[4];
    const float* g2   = (const float*)d_in[5];
    const float* b2   = (const float*)d_in[6];
    const float* fc1w = (const float*)d_in[7];
    const float* fc1b = (const float*)d_in[8];
    const float* dw1w = (const float*)d_in[9];
    const float* dw1b = (const float*)d_in[10];
    const float* fc2w = (const float*)d_in[11];
    const float* fc2b = (const float*)d_in[12];
    const float* dw2w = (const float*)d_in[13];
    const float* dw2b = (const float*)d_in[14];
    const float* fc3w = (const float*)d_in[15];
    const float* fc3b = (const float*)d_in[16];
    const float* gn   = (const float*)d_in[17];
    const float* bn   = (const float*)d_in[18];
    float* out = (float*)d_out;

    u16* tbuf = (u16*)d_ws;                      // NTOT*128 bf16
    u16* h1   = tbuf + (size_t)NTOT * 128;       // NTOT*128 bf16
    u16* h2   = h1 + (size_t)NTOT * 128;         // NTOT*128 bf16
    u16* wfP  = h2 + (size_t)NTOT * 128;         // 16384 u16 each
    u16* wf1  = wfP + 16384;
    u16* wf2  = wf1 + 16384;
    u16* wf3  = wf2 + 16384;
    float* dwT1 = (float*)(wf3 + 16384);         // 27*128 f32
    float* dwT2 = dwT1 + 27 * 128;

    k_prep<<<60, 256, 0, stream>>>(pw, fc1w, fc2w, fc3w, dw1w, dw2w,
                                   wfP, wf1, wf2, wf3, dwT1, dwT2);

    k_proj_ln<<<NTOT / 64, 256, 0, stream>>>(x, wfP, pb, g0, b0, g2, b2, tbuf, h1);
    k_shift_mm<0><<<NTOT / 64, 256, 0, stream>>>(h1, wf1, fc1b, h2);
    k_dw<<<SWD, 256, 0, stream>>>(h2, dwT1, dw1b, h1);
    k_shift_mm<1><<<NTOT / 64, 256, 0, stream>>>(h1, wf2, fc2b, h2);
    k_dw<<<SWD, 256, 0, stream>>>(h2, dwT2, dw2b, h1);
    k_final<<<NTOT / 64, 256, 0, stream>>>(h1, wf3, fc3b, tbuf, gn, bn, out);
}

// Round 7
// 178.551 us; speedup vs baseline: 5.9075x; 1.2459x over previous
//
#include <hip/hip_runtime.h>
#include <hip/hip_bf16.h>
#include <math.h>

#define NTOT 110592   // 48^3
#define SD 48
#define SWD 2304      // 48*48

typedef short s16x8 __attribute__((ext_vector_type(8)));
typedef unsigned short u16x8 __attribute__((ext_vector_type(8)));
typedef float f32x4 __attribute__((ext_vector_type(4)));
typedef unsigned short u16;

__device__ __forceinline__ float bf2f(u16 u) {
    unsigned int x = ((unsigned int)u) << 16;
    float f; __builtin_memcpy(&f, &x, 4); return f;
}
__device__ __forceinline__ u16 f2bf(float f) {
    __hip_bfloat16 h = __float2bfloat16(f);
    u16 u; __builtin_memcpy(&u, &h, 2); return u;
}
__device__ __forceinline__ u16x8 zero8() {
    u16x8 z;
    #pragma unroll
    for (int j = 0; j < 8; ++j) z[j] = 0;
    return z;
}

// fast GELU (tanh form): max abs dev from exact ~1e-3, far under tolerance
__device__ __forceinline__ float gelu_f(float x) {
    float y = x * (0.7978845608f + 0.0356774081f * x * x);   // sqrt(2/pi)(x+0.044715x^3)
    float e = exp2f(y * 2.885390082f);                        // e^{2y}
    return x - x * __builtin_amdgcn_rcpf(e + 1.f);            // x*e/(e+1)
}

// load shifted h[n][cbase..cbase+7] (bf16), axial shift along stride STR.
__device__ __forceinline__ u16x8 ld_shift8(const u16* __restrict__ in, int n, int coord,
                                           int STR, int cbase) {
    int g = cbase / 26;
    int split = 26 * (g + 1) - cbase;     // elems belonging to group g (>=8: no straddle)
    int sh0 = g - 2;
    int cs0 = coord - sh0;
    u16x8 lo = zero8();
    if (cs0 >= 0 && cs0 < SD) lo = *(const u16x8*)&in[(size_t)(n - sh0 * STR) * 128 + cbase];
    if (split >= 8) return lo;
    u16x8 hi = zero8();
    int cs1 = cs0 - 1;
    if (cs1 >= 0 && cs1 < SD) hi = *(const u16x8*)&in[(size_t)(n - (sh0 + 1) * STR) * 128 + cbase];
    u16x8 r;
    #pragma unroll
    for (int j = 0; j < 8; ++j) r[j] = (j < split) ? lo[j] : hi[j];
    return r;
}

// ---------------------------------------------------------------------------
// merged prep: blocks 0-31 pack the 4 fc/proj weights into MFMA fragments;
// blocks 32-59 transpose the 2 depthwise weights to [tap][c]
__global__ __launch_bounds__(256) void k_prep(
    const float* __restrict__ pw, const float* __restrict__ fc1w,
    const float* __restrict__ fc2w, const float* __restrict__ fc3w,
    const float* __restrict__ dw1w, const float* __restrict__ dw2w,
    u16* __restrict__ wfP, u16* __restrict__ wf1, u16* __restrict__ wf2,
    u16* __restrict__ wf3, float* __restrict__ dwT1, float* __restrict__ dwT2)
{
    int b = blockIdx.x;
    if (b < 32) {
        int which = b >> 3;
        const float* src = (which == 0) ? pw : (which == 1) ? fc1w : (which == 2) ? fc2w : fc3w;
        u16* dst = (which == 0) ? wfP : (which == 1) ? wf1 : (which == 2) ? wf2 : wf3;
        int K = (which == 0) ? 108 : 128;
        int idx = (b & 7) * 256 + threadIdx.x;
        int lane = idx & 63;
        int s = (idx >> 6) & 3;
        int t = idx >> 8;
        int co = t * 16 + (lane & 15);
        int kb = s * 32 + (lane >> 4) * 8;
        #pragma unroll
        for (int j = 0; j < 8; ++j) {
            int k = kb + j;
            float v = (k < K) ? src[co * K + k] : 0.f;
            dst[idx * 8 + j] = f2bf(v);
        }
    } else {
        int which = (b - 32) / 14;
        int bb = (b - 32) % 14;
        const float* src = which ? dw2w : dw1w;
        float* dst = which ? dwT2 : dwT1;
        int idx = bb * 256 + threadIdx.x;
        if (idx < 27 * 128) {
            int k = idx >> 7;
            int co = idx & 127;
            dst[idx] = src[co * 27 + k];
        }
    }
}

// ---------------------------------------------------------------------------
// proj conv (im2col MFMA, K=108 pad 128) + LN0 -> t(bf16), LN2 -> h(bf16)
// staging: wave = ci, lane = row; static 3x3x3 tap loop, minimal bounds.
__global__ __launch_bounds__(256) void k_proj_ln(
    const float* __restrict__ x, const u16* __restrict__ wfrag, const float* __restrict__ pb,
    const float* __restrict__ g0, const float* __restrict__ b0,
    const float* __restrict__ g2, const float* __restrict__ b2,
    u16* __restrict__ t_out, u16* __restrict__ h_out)
{
    __shared__ __align__(16) unsigned char smem[32768];   // A(16K) -> Tt(16K)+Th(16K)
    const int tid = threadIdx.x;
    const int n0 = blockIdx.x * 64;

    // im2col gather -> swizzled bf16 LDS [64 rows][128 k]
    {
        const int ci = tid >> 6;    // wave index = input channel
        const int r  = tid & 63;    // row within tile
        const int rsw = (r & 7) << 4;
        unsigned char* dstrow = smem + r * 256;
        int n = n0 + r;
        int oi = n / SWD; int rem = n - oi * SWD;
        int oj = rem / SD; int ok = rem - oj * SD;
        const float* xb = x + (size_t)ci * (96 * 96 * 96);
        const int ik0 = 2 * ok - 1;
        #pragma unroll
        for (int ti = 0; ti < 3; ++ti) {
            int ii = 2 * oi + ti - 1;                 // <= 95 always
            bool iok = (ti > 0) || (ii >= 0);
            #pragma unroll
            for (int tj = 0; tj < 3; ++tj) {
                int ij = 2 * oj + tj - 1;             // <= 95 always
                bool jok = (tj > 0) || (ij >= 0);
                const float* row = xb + ((size_t)ii * 96 + ij) * 96;
                const int kbase = ci * 27 + ti * 9 + tj * 3;
                #pragma unroll
                for (int tk = 0; tk < 3; ++tk) {
                    int ik = ik0 + tk;                // <= 95 always
                    bool kok = (tk > 0) || (ik >= 0);
                    float v = (iok && jok && kok) ? row[ik] : 0.f;
                    int k = kbase + tk;
                    *(u16*)(dstrow + ((2 * k) ^ rsw)) = f2bf(v);
                }
            }
        }
        // zero-pad k = 108..127 (each ci writes 5)
        #pragma unroll
        for (int p = 0; p < 5; ++p) {
            int k = 108 + ci * 5 + p;
            *(u16*)(dstrow + ((2 * k) ^ rsw)) = 0;
        }
    }
    __syncthreads();

    const int lane = tid & 63;
    const int wv = tid >> 6;
    const int rb = wv * 16;
    const int colb = lane & 15;
    const int q = lane >> 4;
    const int arow = rb + colb;
    const int aswz = (arow & 7) << 4;

    f32x4 acc[8];
    #pragma unroll
    for (int t = 0; t < 8; ++t) {
        float bb = pb[t * 16 + colb];
        acc[t][0] = bb; acc[t][1] = bb; acc[t][2] = bb; acc[t][3] = bb;
    }
    #pragma unroll
    for (int s = 0; s < 4; ++s) {
        s16x8 a = *(const s16x8*)(smem + arow * 256 + ((s * 64 + q * 16) ^ aswz));
        #pragma unroll
        for (int t = 0; t < 8; ++t) {
            s16x8 b = *(const s16x8*)&wfrag[((t * 4 + s) * 64 + lane) * 8];
            acc[t] = __builtin_amdgcn_mfma_f32_16x16x32_bf16(a, b, acc[t], 0, 0, 0);
        }
    }

    // LN0 stats in regs
    float s1[4] = {0.f,0.f,0.f,0.f}, s2[4] = {0.f,0.f,0.f,0.f};
    #pragma unroll
    for (int t = 0; t < 8; ++t)
        #pragma unroll
        for (int r4 = 0; r4 < 4; ++r4) {
            float v = acc[t][r4];
            s1[r4] += v; s2[r4] += v * v;
        }
    #pragma unroll
    for (int r4 = 0; r4 < 4; ++r4)
        #pragma unroll
        for (int m = 1; m < 16; m <<= 1) {
            s1[r4] += __shfl_xor(s1[r4], m);
            s2[r4] += __shfl_xor(s2[r4], m);
        }

    float g0v[8], b0v[8], g2v[8], b2v[8];
    #pragma unroll
    for (int t = 0; t < 8; ++t) {
        int c = t * 16 + colb;
        g0v[t] = g0[c]; b0v[t] = b0[c]; g2v[t] = g2[c]; b2v[t] = b2[c];
    }

    float tval[8][4];
    float u1[4] = {0.f,0.f,0.f,0.f}, u2[4] = {0.f,0.f,0.f,0.f};
    #pragma unroll
    for (int r4 = 0; r4 < 4; ++r4) {
        float mean = s1[r4] * (1.f / 128.f);
        float var  = fmaxf(s2[r4] * (1.f / 128.f) - mean * mean, 0.f);
        float rstd = rsqrtf(var + 1e-5f);
        #pragma unroll
        for (int t = 0; t < 8; ++t) {
            float tv = (acc[t][r4] - mean) * rstd * g0v[t] + b0v[t];
            tval[t][r4] = tv;
            u1[r4] += tv; u2[r4] += tv * tv;
        }
    }
    #pragma unroll
    for (int r4 = 0; r4 < 4; ++r4)
        #pragma unroll
        for (int m = 1; m < 16; m <<= 1) {
            u1[r4] += __shfl_xor(u1[r4], m);
            u2[r4] += __shfl_xor(u2[r4], m);
        }
    __syncthreads();   // A dead; reuse LDS for t/h dumps

    #pragma unroll
    for (int r4 = 0; r4 < 4; ++r4) {
        float mean2 = u1[r4] * (1.f / 128.f);
        float var2  = fmaxf(u2[r4] * (1.f / 128.f) - mean2 * mean2, 0.f);
        float rstd2 = rsqrtf(var2 + 1e-5f);
        int row = rb + q * 4 + r4;
        int rsw = (row & 7) << 4;
        #pragma unroll
        for (int t = 0; t < 8; ++t) {
            int col = t * 16 + colb;
            float tv = tval[t][r4];
            float hv = (tv - mean2) * rstd2 * g2v[t] + b2v[t];
            int off = (2 * col) ^ rsw;
            *(u16*)(smem + row * 256 + off)         = f2bf(tv);
            *(u16*)(smem + 16384 + row * 256 + off) = f2bf(hv);
        }
    }
    __syncthreads();
    for (int i = tid; i < 1024; i += 256) {
        int row = i >> 4;
        int c8 = (i & 15) * 8;
        int byte = row * 256 + ((2 * c8) ^ ((row & 7) << 4));
        *(u16x8*)&t_out[(size_t)(n0 + row) * 128 + c8] = *(const u16x8*)(smem + byte);
        *(u16x8*)&h_out[(size_t)(n0 + row) * 128 + c8] = *(const u16x8*)(smem + 16384 + byte);
    }
}

// ---------------------------------------------------------------------------
// axial shift + matmul, no A-LDS: activation fragments loaded directly from
// global with shift applied in the address. 64 rows/block, 4 waves.
template <int AXIS>
__global__ __launch_bounds__(256) void k_shift_mm(
    const u16* __restrict__ in, const u16* __restrict__ wfrag, const float* __restrict__ bias,
    u16* __restrict__ out)
{
    __shared__ u16 O[64 * 136];   // 17.4 KB output staging
    const int tid = threadIdx.x;
    const int n0 = blockIdx.x * 64;
    const int lane = tid & 63;
    const int wv = tid >> 6;
    const int colb = lane & 15;
    const int q = lane >> 4;

    const int arow = wv * 16 + colb;
    const int n = n0 + arow;
    const int STR = (AXIS == 0) ? SWD : (AXIS == 1) ? SD : 1;
    const int coord = (AXIS == 0) ? n / SWD : (AXIS == 1) ? (n / SD) % SD : n % SD;

    f32x4 acc[8];
    #pragma unroll
    for (int t = 0; t < 8; ++t) {
        float bb = bias[t * 16 + colb];
        acc[t][0] = bb; acc[t][1] = bb; acc[t][2] = bb; acc[t][3] = bb;
    }
    #pragma unroll
    for (int s = 0; s < 4; ++s) {
        u16x8 av = ld_shift8(in, n, coord, STR, s * 32 + q * 8);
        s16x8 a = *(s16x8*)&av;
        #pragma unroll
        for (int t = 0; t < 8; ++t) {
            s16x8 b = *(const s16x8*)&wfrag[((t * 4 + s) * 64 + lane) * 8];
            acc[t] = __builtin_amdgcn_mfma_f32_16x16x32_bf16(a, b, acc[t], 0, 0, 0);
        }
    }
    // stage D (row = n-within-tile = q*4+r4, col = co = t*16+colb) into LDS
    #pragma unroll
    for (int r4 = 0; r4 < 4; ++r4) {
        int row = wv * 16 + q * 4 + r4;
        #pragma unroll
        for (int t = 0; t < 8; ++t)
            O[row * 136 + t * 16 + colb] = f2bf(acc[t][r4]);
    }
    __syncthreads();
    for (int i = tid; i < 1024; i += 256) {
        int row = i >> 4;
        int c8 = (i & 15) * 8;
        *(u16x8*)&out[(size_t)(n0 + row) * 128 + c8] = *(const u16x8*)&O[row * 136 + c8];
    }
}

// ---------------------------------------------------------------------------
// depthwise 3x3x3 conv, bf16 io; wt f32 [27 taps][128 c]; thread: 8 ch x 3 k.
// 2-deep software pipeline over the 9 (di,dj) taps; clamped addresses +
// block-uniform compute-skip for spatial OOB; XCD-chunked block swizzle.
__global__ __launch_bounds__(256, 4) void k_dw(
    const u16* __restrict__ in, const float* __restrict__ wt, const float* __restrict__ b,
    u16* __restrict__ out)
{
    const int tid = threadIdx.x;
    const int cg = tid & 15;       // c = cg*8
    const int kq = tid >> 4;       // 0..15 -> k0 = kq*3
    const int k0 = kq * 3;
    const int bid = blockIdx.x;
    const int ij = (bid & 7) * 288 + (bid >> 3);   // XCD chunk: 6 i-rows per XCD
    const int i = ij / SD;
    const int j = ij - i * SD;
    const int c = cg * 8;

    // clamped k addresses for the 5-slot window (slots 1..3 always in-bounds)
    const int kclamp0 = (k0 - 1 < 0) ? 0 : (k0 - 1);
    const int kclamp4 = (k0 + 3 > SD - 1) ? (SD - 1) : (k0 + 3);
    const bool k0bad = (k0 - 1 < 0);
    const bool k4bad = (k0 + 3 > SD - 1);

    float acc[3][8];
    {
        float4 ba = *(const float4*)&b[c];
        float4 bb = *(const float4*)&b[c + 4];
        #pragma unroll
        for (int t = 0; t < 3; ++t) {
            acc[t][0] = ba.x; acc[t][1] = ba.y; acc[t][2] = ba.z; acc[t][3] = ba.w;
            acc[t][4] = bb.x; acc[t][5] = bb.y; acc[t][6] = bb.z; acc[t][7] = bb.w;
        }
    }

    // per-tap validity + clamped base pointers (block-uniform)
    bool okt[9];
    const u16* baseptr[9];
    #pragma unroll
    for (int t9 = 0; t9 < 9; ++t9) {
        int di = t9 / 3 - 1, dj = t9 % 3 - 1;
        int ii = i + di, jj = j + dj;
        okt[t9] = ((unsigned)ii < SD) && ((unsigned)jj < SD);
        int iic = (ii < 0) ? 0 : (ii > SD - 1 ? SD - 1 : ii);
        int jjc = (jj < 0) ? 0 : (jj > SD - 1 ? SD - 1 : jj);
        baseptr[t9] = &in[(size_t)((iic * SD + jjc) * SD) * 128 + c];
    }

    u16x8 win[2][5];
    // prologue: issue tap 0 window loads
    {
        const u16* base = baseptr[0];
        win[0][0] = *(const u16x8*)(base + (size_t)kclamp0 * 128);
        win[0][1] = *(const u16x8*)(base + (size_t)(k0    ) * 128);
        win[0][2] = *(const u16x8*)(base + (size_t)(k0 + 1) * 128);
        win[0][3] = *(const u16x8*)(base + (size_t)(k0 + 2) * 128);
        win[0][4] = *(const u16x8*)(base + (size_t)kclamp4 * 128);
    }

    #pragma unroll
    for (int t9 = 0; t9 < 9; ++t9) {
        const int cur = t9 & 1;
        // issue next tap's loads before consuming current (prefetch distance 1)
        if (t9 < 8) {
            const u16* base = baseptr[t9 + 1];
            win[cur ^ 1][0] = *(const u16x8*)(base + (size_t)kclamp0 * 128);
            win[cur ^ 1][1] = *(const u16x8*)(base + (size_t)(k0    ) * 128);
            win[cur ^ 1][2] = *(const u16x8*)(base + (size_t)(k0 + 1) * 128);
            win[cur ^ 1][3] = *(const u16x8*)(base + (size_t)(k0 + 2) * 128);
            win[cur ^ 1][4] = *(const u16x8*)(base + (size_t)kclamp4 * 128);
        }
        if (okt[t9]) {   // block-uniform branch
            const int tap0 = t9 * 3;
            float wv[3][8];
            #pragma unroll
            for (int dk = 0; dk < 3; ++dk) {
                float4 wa = *(const float4*)&wt[(tap0 + dk) * 128 + c];
                float4 wb = *(const float4*)&wt[(tap0 + dk) * 128 + c + 4];
                wv[dk][0] = wa.x; wv[dk][1] = wa.y; wv[dk][2] = wa.z; wv[dk][3] = wa.w;
                wv[dk][4] = wb.x; wv[dk][5] = wb.y; wv[dk][6] = wb.z; wv[dk][7] = wb.w;
            }
            #pragma unroll
            for (int s = 0; s < 5; ++s) {
                bool bad = (s == 0 && k0bad) || (s == 4 && k4bad);
                float vs[8];
                #pragma unroll
                for (int m = 0; m < 8; ++m)
                    vs[m] = bad ? 0.f : bf2f(win[cur][s][m]);
                // slot s feeds output t with dk = s - t, t in [max(0,s-2), min(2,s)]
                #pragma unroll
                for (int t = 0; t < 3; ++t) {
                    int dk = s - t;
                    if (dk >= 0 && dk < 3) {
                        #pragma unroll
                        for (int m = 0; m < 8; ++m)
                            acc[t][m] = fmaf(wv[dk][m], vs[m], acc[t][m]);
                    }
                }
            }
        }
    }
    #pragma unroll
    for (int t = 0; t < 3; ++t) {
        u16x8 o;
        #pragma unroll
        for (int m = 0; m < 8; ++m) o[m] = f2bf(acc[t][m]);
        *(u16x8*)&out[(size_t)((i * SD + j) * SD + k0 + t) * 128 + c] = o;
    }
}

// ---------------------------------------------------------------------------
// shift-D + fc3 (swapped MFMA, direct global B-frags) + fast GELU + residual
// + wave-local LN + transposed store. Wave = one 16-row n-tile; LDS = T only.
__global__ __launch_bounds__(256) void k_final(
    const u16* __restrict__ in, const u16* __restrict__ wfrag, const float* __restrict__ bias,
    const u16* __restrict__ tin, const float* __restrict__ gn, const float* __restrict__ bn,
    float* __restrict__ out)
{
    __shared__ u16 T[64 * 136];   // residual tile, 17.4 KB
    const int tid = threadIdx.x;
    const int n0 = blockIdx.x * 64;
    const int lane = tid & 63;
    const int wv = tid >> 6;       // = n-tile (tb)
    const int colb = lane & 15;
    const int q = lane >> 4;

    // stage residual t tile (coalesced u16x8)
    for (int i = tid; i < 1024; i += 256) {
        int row = i >> 4;
        int c8 = (i & 15) * 8;
        *(u16x8*)&T[row * 136 + c8] = *(const u16x8*)&tin[(size_t)(n0 + row) * 128 + c8];
    }

    const int nn = wv * 16 + colb;    // this lane's output row (D col)
    const int n = n0 + nn;
    const int coord = n % SD;

    // acc[ta]: D rows = co = ta*16 + q*4 + r4, D col = nn
    f32x4 acc[8];
    #pragma unroll
    for (int ta = 0; ta < 8; ++ta)
        #pragma unroll
        for (int r4 = 0; r4 < 4; ++r4)
            acc[ta][r4] = bias[ta * 16 + q * 4 + r4];

    #pragma unroll
    for (int s = 0; s < 4; ++s) {
        u16x8 bv = ld_shift8(in, n, coord, 1, s * 32 + q * 8);
        s16x8 b = *(s16x8*)&bv;
        #pragma unroll
        for (int ta = 0; ta < 8; ++ta) {
            s16x8 a = *(const s16x8*)&wfrag[((ta * 4 + s) * 64 + lane) * 8];
            acc[ta] = __builtin_amdgcn_mfma_f32_16x16x32_bf16(a, b, acc[ta], 0, 0, 0);
        }
    }
    __syncthreads();   // T ready

    // GELU + residual + full-128 LN stats (wave-local: butterfly over q)
    float val[8][4];
    float s1 = 0.f, s2 = 0.f;
    #pragma unroll
    for (int ta = 0; ta < 8; ++ta)
        #pragma unroll
        for (int r4 = 0; r4 < 4; ++r4) {
            int co = ta * 16 + q * 4 + r4;
            float v = gelu_f(acc[ta][r4]) + bf2f(T[nn * 136 + co]);
            val[ta][r4] = v;
            s1 += v; s2 += v * v;
        }
    s1 += __shfl_xor(s1, 16); s2 += __shfl_xor(s2, 16);
    s1 += __shfl_xor(s1, 32); s2 += __shfl_xor(s2, 32);
    float mean = s1 * (1.f / 128.f);
    float var  = fmaxf(s2 * (1.f / 128.f) - mean * mean, 0.f);
    float rstd = rsqrtf(var + 1e-5f);

    #pragma unroll
    for (int ta = 0; ta < 8; ++ta)
        #pragma unroll
        for (int r4 = 0; r4 < 4; ++r4) {
            int co = ta * 16 + q * 4 + r4;
            float o = (val[ta][r4] - mean) * rstd * gn[co] + bn[co];
            out[(size_t)co * NTOT + n] = o;
        }
}

// ---------------------------------------------------------------------------
extern "C" void kernel_launch(void* const* d_in, const int* in_sizes, int n_in,
                              void* d_out, int out_size, void* d_ws, size_t ws_size,
                              hipStream_t stream)
{
    const float* x    = (const float*)d_in[0];
    const float* pw   = (const float*)d_in[1];
    const float* pb   = (const float*)d_in[2];
    const float* g0   = (const float*)d_in[3];
    const float* b0   = (const float*)d_in[4];
    const float* g2   = (const float*)d_in[5];
    const float* b2   = (const float*)d_in[6];
    const float* fc1w = (const float*)d_in[7];
    const float* fc1b = (const float*)d_in[8];
    const float* dw1w = (const float*)d_in[9];
    const float* dw1b = (const float*)d_in[10];
    const float* fc2w = (const float*)d_in[11];
    const float* fc2b = (const float*)d_in[12];
    const float* dw2w = (const float*)d_in[13];
    const float* dw2b = (const float*)d_in[14];
    const float* fc3w = (const float*)d_in[15];
    const float* fc3b = (const float*)d_in[16];
    const float* gn   = (const float*)d_in[17];
    const float* bn   = (const float*)d_in[18];
    float* out = (float*)d_out;

    u16* tbuf = (u16*)d_ws;                      // NTOT*128 bf16
    u16* h1   = tbuf + (size_t)NTOT * 128;       // NTOT*128 bf16
    u16* h2   = h1 + (size_t)NTOT * 128;         // NTOT*128 bf16
    u16* wfP  = h2 + (size_t)NTOT * 128;         // 16384 u16 each
    u16* wf1  = wfP + 16384;
    u16* wf2  = wf1 + 16384;
    u16* wf3  = wf2 + 16384;
    float* dwT1 = (float*)(wf3 + 16384);         // 27*128 f32
    float* dwT2 = dwT1 + 27 * 128;

    k_prep<<<60, 256, 0, stream>>>(pw, fc1w, fc2w, fc3w, dw1w, dw2w,
                                   wfP, wf1, wf2, wf3, dwT1, dwT2);

    k_proj_ln<<<NTOT / 64, 256, 0, stream>>>(x, wfP, pb, g0, b0, g2, b2, tbuf, h1);
    k_shift_mm<0><<<NTOT / 64, 256, 0, stream>>>(h1, wf1, fc1b, h2);
    k_dw<<<SWD, 256, 0, stream>>>(h2, dwT1, dw1b, h1);
    k_shift_mm<1><<<NTOT / 64, 256, 0, stream>>>(h1, wf2, fc2b, h2);
    k_dw<<<SWD, 256, 0, stream>>>(h2, dwT2, dw2b, h1);
    k_final<<<NTOT / 64, 256, 0, stream>>>(h1, wf3, fc3b, tbuf, gn, bn, out);
}